// Round 5
// baseline (295.101 us; speedup 1.0000x reference)
//
#include <hip/hip_runtime.h>
#include <math.h>

#define NR 5
#define NB 7
#define NS 119
#define NA 25000
#define NE 1000000
#define OC 360           // output columns per atom
#define MUS 100          // unique moment floats per atom
#define CAPI 112         // id bin capacity (lambda=40, max ~68, overflow ~1e-15)
#define CHUNK 32         // atoms per accum/contract block (8 sub-lanes each)
#define MPAD 101         // LDS stride: gcd(101,32)=1 -> conflict-free
#define CROW 36          // padded coeffs row: 35 floats + 1 pad = 144B, float4-aligned

// tril index tables (wave-uniform index -> scalar loads)
static constexpr int T2I[15] = {0,1,1,2,2,2,3,3,3,3,4,4,4,4,4};
static constexpr int T2J[15] = {0,0,1,0,1,2,0,1,2,3,0,1,2,3,4};
static constexpr int T3I[35] = {0,1,1,1,2,2,2,2,2,2,3,3,3,3,3,3,3,3,3,3,4,4,4,4,4,4,4,4,4,4,4,4,4,4,4};
static constexpr int T3J[35] = {0,0,1,1,0,1,1,2,2,2,0,1,1,2,2,2,3,3,3,3,0,1,1,2,2,2,3,3,3,3,4,4,4,4,4};
static constexpr int T3K[35] = {0,0,0,1,0,0,1,0,1,2,0,0,1,0,1,2,0,1,2,3,0,0,1,0,1,2,0,1,2,3,0,1,2,3,4};

static constexpr int P2[9]  = {0,1,2, 1,3,4, 2,4,5};
static constexpr int P3[27] = {0,1,4, 1,2,5, 4,5,7,
                               1,2,5, 2,3,6, 5,6,8,
                               4,5,7, 5,6,8, 7,8,9};
static constexpr float W2[6]  = {1.f,2.f,2.f,1.f,2.f,1.f};
static constexpr float W3[10] = {1.f,3.f,3.f,1.f,3.f,6.f,3.f,3.f,3.f,1.f};

// ============================ FAST PATH ==================================
// R4 post-mortem: alignment fix removed 31MB writes, time unchanged at ~85us
// with VALU 7% / HBM 14% -> every in-structure fix (atomic padding, atomic
// hoist, gather vectorization, alignment) is null. The fused kernel's cost
// is structural: the 1M-atomic + random-scatter stream. This round DECOMPOSES
// it into three separately-profiled kernels to isolate the serial resource.

// pass 0: repack coeffs rows 35 -> 36 floats (144B, float4-aligned).
__global__ __launch_bounds__(256) void transpose_coeffs_kernel(
    const float* __restrict__ src, float* __restrict__ dst)
{
    int t = blockIdx.x * 256 + threadIdx.x;
    const int TOT = NS * NS * (NR * NB);
    if (t >= TOT) return;
    int pair = t / 35, rem = t - pair * 35;
    dst[pair * CROW + rem] = src[t];
}

// pass 1a: pure streaming edge compute. Record written IN EDGE ORDER
// (coalesced float4 x2, 32MB). No atomic, no scatter. Roofline ~52MB of
// traffic -> should run at HBM-streaming speed (~15-25us).
__global__ __launch_bounds__(256) void edge_compute_kernel(
    const float* __restrict__ dr_vec, const int* __restrict__ Z,
    const int* __restrict__ nbr, const float* __restrict__ coeffsT,
    float* __restrict__ edgerec)
{
    int e = blockIdx.x * 256 + threadIdx.x;
    if (e >= NE) return;

    int ai = nbr[e];
    int aj = nbr[NE + e];
    float x = dr_vec[3*e+0], y = dr_vec[3*e+1], z = dr_vec[3*e+2];
    int Zi = Z[ai], Zj = Z[aj];

    const float4* c4 = (const float4*)(coeffsT + (size_t)(Zi*NS + Zj) * CROW);
    float4 cw[9];
#pragma unroll
    for (int k = 0; k < 9; k++) cw[k] = c4[k];
    const float* cf = (const float*)&cw[0];

    float dr  = sqrtf(x*x + y*y + z*z);
    float inv = 1.0f / (dr + 1e-5f);
    float d0 = x*inv, d1 = y*inv, d2 = z*inv;

    const float PI_F = 3.14159265358979323846f;
    const float betta = 49.0f / 36.0f;
    float rad_norm = powf(2.0f * betta / PI_F, 0.75f);
    float cut = (dr < 6.0f) ? 0.5f*(cosf(PI_F * dr * (1.0f/6.0f)) + 1.0f) : 0.0f;
    float scale = cut * 0.3779644730092272272f;   // 1/sqrt(7)

    float basis[NB];
#pragma unroll
    for (int b = 0; b < NB; b++) {
        float t = dr - (float)b;
        basis[b] = rad_norm * expf(-betta * t * t);
    }

    float rad[NR];
#pragma unroll
    for (int r = 0; r < NR; r++) {
        float s = 0.f;
#pragma unroll
        for (int b = 0; b < NB; b++) s += basis[b] * cf[r*NB + b];
        rad[r] = s * scale;
    }

    float4* rp = (float4*)(edgerec + (size_t)e * 8);
    rp[0] = make_float4(rad[0], rad[1], rad[2], rad[3]);
    rp[1] = make_float4(rad[4], d0, d1, d2);
}

// pass 1b: ISOLATED atomic+scatter. Only the fetch_add and a 4B id write.
// This kernel's standalone duration is the round's key measurement:
// >=60us -> atomics are the serial resource (next: K-way split counters);
// <=20us -> the decomposition itself banks the win.
__global__ __launch_bounds__(256) void id_scatter_kernel(
    const int* __restrict__ nbr, int* __restrict__ cursor, int* __restrict__ bins)
{
    int e = blockIdx.x * 256 + threadIdx.x;
    if (e >= NE) return;
    int aj = nbr[NE + e];
    int pos = __hip_atomic_fetch_add(&cursor[aj], 1, __ATOMIC_RELAXED, __HIP_MEMORY_SCOPE_AGENT);
    if (pos < CAPI) bins[(size_t)aj * CAPI + pos] = e;
}

// pass 2: accumulate (gather records by id; edgerec is L2/L3-resident) +
// contract. CHUNK=32 atoms/block, 8 sub-lanes/atom -> 782 blocks for
// gather-latency hiding.
__global__ __launch_bounds__(256) void accum_contract_kernel(
    const int* __restrict__ cursor, const int* __restrict__ bins,
    const float* __restrict__ edgerec, float* __restrict__ out)
{
    __shared__ float lds[CHUNK * MPAD];
    int base = blockIdx.x * CHUNK;
    int nat  = min(CHUNK, NA - base);

    int al  = threadIdx.x >> 3;          // local atom 0..31
    int sub = threadIdx.x & 7;
    int a   = base + al;
    int n   = (a < NA) ? min(cursor[a], CAPI) : 0;

    float acc[MUS];
#pragma unroll
    for (int i = 0; i < MUS; i++) acc[i] = 0.f;

    const int* mybin = bins + (size_t)a * CAPI;
    for (int p = sub; p < n; p += 8) {
        int e = mybin[p];
        const float4* rp = (const float4*)(edgerec + (size_t)e * 8);
        float4 r0 = rp[0], r1 = rp[1];
        float rad[NR] = {r0.x, r0.y, r0.z, r0.w, r1.x};
        float d0 = r1.y, d1 = r1.z, d2 = r1.w;

        float q2[6] = {d0*d0, d1*d0, d2*d0, d1*d1, d2*d1, d2*d2};
        float q3[10] = {d0*q2[0], d1*q2[0], d0*q2[3], d1*q2[3], d2*q2[0],
                        d2*q2[1], d2*q2[3], d0*q2[5], d1*q2[5], d2*q2[5]};

#pragma unroll
        for (int r = 0; r < NR; r++) {
            float rv = rad[r];
            acc[r] += rv;
            acc[5 + r*3 + 0] += rv*d0;
            acc[5 + r*3 + 1] += rv*d1;
            acc[5 + r*3 + 2] += rv*d2;
#pragma unroll
            for (int q = 0; q < 6; q++)  acc[20 + r*6  + q] += rv*q2[q];
#pragma unroll
            for (int q = 0; q < 10; q++) acc[50 + r*10 + q] += rv*q3[q];
        }
    }

    // reduce over 8 sub-lanes (within-wave groups), deposit into LDS tile
#pragma unroll
    for (int i = 0; i < MUS; i++) {
        float v = acc[i];
        v += __shfl_xor(v, 1, 64);
        v += __shfl_xor(v, 2, 64);
        v += __shfl_xor(v, 4, 64);
        if (sub == 0) lds[al * MPAD + i] = v;
    }
    __syncthreads();

    // ---- contract phase: lanes = atoms (lane<32 valid), 4 waves x 90 cols --
    int wave = threadIdx.x >> 6, lane = threadIdx.x & 63;
    int a2 = base + lane;
    bool valid = (lane < nat);
    int mb = lane * MPAD;

#define ML(o) lds[mb + (o)]

    for (int cc = wave; cc < 360; cc += 4) {
        if (!valid) continue;
        float v; int dest;

        if (cc < 5) {
            v = ML(cc);
            dest = a2 * OC + cc;
        } else if (cc < 20) {
            int l = cc - 5;
            int r = T2I[l], s = T2J[l];
            float acc2 = 0.f;
#pragma unroll
            for (int i = 0; i < 3; i++) acc2 += ML(5 + r*3 + i) * ML(5 + s*3 + i);
            v = acc2;
            int f = l * NA + a2; int aa = f / 15; dest = aa * OC + 5 + (f - aa*15);
        } else if (cc < 35) {
            int l = cc - 20;
            int r = T2I[l], s = T2J[l];
            float acc2 = 0.f;
#pragma unroll
            for (int p = 0; p < 6; p++) acc2 += W2[p] * ML(20 + r*6 + p) * ML(20 + s*6 + p);
            v = acc2;
            int f = l * NA + a2; int aa = f / 15; dest = aa * OC + 20 + (f - aa*15);
        } else if (cc < 50) {
            int l = cc - 35;
            int r = T2I[l], s = T2J[l];
            float acc2 = 0.f;
#pragma unroll
            for (int p = 0; p < 10; p++) acc2 += W3[p] * ML(50 + r*10 + p) * ML(50 + s*10 + p);
            v = acc2;
            int f = l * NA + a2; int aa = f / 15; dest = aa * OC + 35 + (f - aa*15);
        } else if (cc < 85) {
            int l = cc - 50;
            int r = T3I[l], s = T3J[l], t = T3K[l];
            float R[6], S[6], T[6];
#pragma unroll
            for (int p = 0; p < 6; p++) { R[p]=ML(20+r*6+p); S[p]=ML(20+s*6+p); T[p]=ML(20+t*6+p); }
            float acc2 = 0.f;
#pragma unroll
            for (int i = 0; i < 3; i++)
#pragma unroll
            for (int j = 0; j < 3; j++)
#pragma unroll
            for (int k = 0; k < 3; k++)
                acc2 += R[P2[i*3+j]] * S[P2[i*3+k]] * T[P2[j*3+k]];
            v = acc2;
            int f = l * NA + a2; int aa = f / 35; dest = aa * OC + 50 + (f - aa*35);
        } else if (cc < 160) {
            int l = cc - 85;
            int p = l / 5, t = l - p*5;
            int r = T2I[p], s = T2J[p];
            float T[6];
#pragma unroll
            for (int q = 0; q < 6; q++) T[q] = ML(20 + t*6 + q);
            float acc2 = 0.f;
#pragma unroll
            for (int i = 0; i < 3; i++)
#pragma unroll
            for (int j = 0; j < 3; j++)
                acc2 += ML(5 + r*3 + i) * ML(5 + s*3 + j) * T[P2[i*3+j]];
            v = acc2;
            int f = l * NA + a2; int aa = f / 75; dest = aa * OC + 85 + (f - aa*75);
        } else if (cc < 235) {
            int l = cc - 160;
            int p = l / 5, t = l - p*5;
            int r = T2I[p], s = T2J[p];
            float R[10], S[10], T[6];
#pragma unroll
            for (int q = 0; q < 10; q++) { R[q]=ML(50+r*10+q); S[q]=ML(50+s*10+q); }
#pragma unroll
            for (int q = 0; q < 6;  q++) T[q] = ML(20 + t*6 + q);
            float acc2 = 0.f;
#pragma unroll
            for (int k = 0; k < 3; k++)
#pragma unroll
            for (int l2 = 0; l2 < 3; l2++) {
                float inner = 0.f;
#pragma unroll
                for (int i = 0; i < 3; i++)
#pragma unroll
                for (int j = 0; j < 3; j++)
                    inner += R[P3[(i*3+j)*3+k]] * S[P3[(i*3+j)*3+l2]];
                acc2 += inner * T[P2[k*3+l2]];
            }
            v = acc2;
            int f = l * NA + a2; int aa = f / 75; dest = aa * OC + 160 + (f - aa*75);
        } else {
            int l = cc - 235;
            int r = l / 25; int rem = l - r*25; int s = rem / 5; int t = rem - s*5;
            float R[10], S[6], T1[3];
#pragma unroll
            for (int q = 0; q < 10; q++) R[q] = ML(50 + r*10 + q);
#pragma unroll
            for (int q = 0; q < 6;  q++) S[q] = ML(20 + s*6 + q);
#pragma unroll
            for (int q = 0; q < 3;  q++) T1[q] = ML(5 + t*3 + q);
            float acc2 = 0.f;
#pragma unroll
            for (int i = 0; i < 3; i++)
#pragma unroll
            for (int j = 0; j < 3; j++)
#pragma unroll
            for (int k = 0; k < 3; k++)
                acc2 += R[P3[(i*3+j)*3+k]] * S[P2[i*3+j]] * T1[k];
            v = acc2;
            int f = l * NA + a2; int aa = f / 125; dest = aa * OC + 235 + (f - aa*125);
        }
        out[dest] = v;
    }
#undef ML
}

// ========================= FALLBACK PATH =======================
__global__ __launch_bounds__(256) void scatter_kernel(
    const int* __restrict__ nbr, int* __restrict__ cursor, int* __restrict__ bins)
{
    int e = blockIdx.x * 256 + threadIdx.x;
    if (e >= NE) return;
    int aj = nbr[NE + e];
    int pos = __hip_atomic_fetch_add(&cursor[aj], 1, __ATOMIC_RELAXED, __HIP_MEMORY_SCOPE_AGENT);
    if (pos < CAPI) bins[(size_t)aj * CAPI + pos] = e;
}

__global__ __launch_bounds__(256) void accum_kernel(
    const float* __restrict__ dr_vec, const int* __restrict__ Z,
    const int* __restrict__ nbr, const float* __restrict__ coeffs,
    const int* __restrict__ cursor, const int* __restrict__ bins,
    float* __restrict__ Mu)
{
    __shared__ float red[32 * MUS];
    int t   = blockIdx.x * 256 + threadIdx.x;
    int a   = t >> 3;
    int sub = t & 7;
    int al  = threadIdx.x >> 3;
    int n   = (a < NA) ? min(cursor[a], CAPI) : 0;
    int Zj  = (a < NA) ? Z[a] : 0;

    float acc[MUS];
#pragma unroll
    for (int i = 0; i < MUS; i++) acc[i] = 0.f;

    const int* mybin = bins + (size_t)a * CAPI;
    const float PI_F = 3.14159265358979323846f;
    const float betta = 49.0f / 36.0f;
    float rad_norm = powf(2.0f * betta / PI_F, 0.75f);

    for (int p = sub; p < n; p += 8) {
        int e = mybin[p];
        float x = dr_vec[3*e+0], y = dr_vec[3*e+1], z = dr_vec[3*e+2];
        int Zi = Z[nbr[e]];

        float dr  = sqrtf(x*x + y*y + z*z);
        float inv = 1.0f / (dr + 1e-5f);
        float d0 = x*inv, d1 = y*inv, d2 = z*inv;

        float cut = (dr < 6.0f) ? 0.5f*(cosf(PI_F * dr * (1.0f/6.0f)) + 1.0f) : 0.0f;
        float scale = cut * 0.3779644730092272272f;

        float basis[NB];
#pragma unroll
        for (int b = 0; b < NB; b++) {
            float tt = dr - (float)b;
            basis[b] = rad_norm * expf(-betta * tt * tt);
        }

        const float* cp = coeffs + ((size_t)(Zi*NS + Zj)) * (NR*NB);
        float rad[NR];
#pragma unroll
        for (int r = 0; r < NR; r++) {
            float s = 0.f;
#pragma unroll
            for (int b = 0; b < NB; b++) s += basis[b] * cp[r*NB + b];
            rad[r] = s * scale;
        }

        float q2[6] = {d0*d0, d1*d0, d2*d0, d1*d1, d2*d1, d2*d2};
        float q3[10] = {d0*q2[0], d1*q2[0], d0*q2[3], d1*q2[3], d2*q2[0],
                        d2*q2[1], d2*q2[3], d0*q2[5], d1*q2[5], d2*q2[5]};

#pragma unroll
        for (int r = 0; r < NR; r++) {
            float rv = rad[r];
            acc[r] += rv;
            acc[5 + r*3 + 0] += rv*d0;
            acc[5 + r*3 + 1] += rv*d1;
            acc[5 + r*3 + 2] += rv*d2;
#pragma unroll
            for (int q = 0; q < 6; q++)  acc[20 + r*6  + q] += rv*q2[q];
#pragma unroll
            for (int q = 0; q < 10; q++) acc[50 + r*10 + q] += rv*q3[q];
        }
    }

#pragma unroll
    for (int i = 0; i < MUS; i++) {
        float v = acc[i];
        v += __shfl_xor(v, 1, 64);
        v += __shfl_xor(v, 2, 64);
        v += __shfl_xor(v, 4, 64);
        if (sub == 0) red[al * MUS + i] = v;
    }
    __syncthreads();

    for (int u = threadIdx.x; u < 32 * MUS; u += 256) {
        int ga = blockIdx.x * 32 + u / MUS;
        if (ga < NA) Mu[(size_t)ga * MUS + (u - (u / MUS) * MUS)] = red[u];
    }
}

__global__ __launch_bounds__(256) void contract_kernel(
    const float* __restrict__ Mu, float* __restrict__ out)
{
    __shared__ float lds[64 * MPAD];
    int base = blockIdx.x * 64;
    int nat  = min(64, NA - base);

    for (int t = threadIdx.x; t < nat * MUS; t += 256) {
        int al = t / MUS, off = t - al * MUS;
        lds[al * MPAD + off] = Mu[(size_t)base * MUS + t];
    }
    __syncthreads();

    int wave = threadIdx.x >> 6, lane = threadIdx.x & 63;
    int a2 = base + lane;
    bool valid = (lane < nat);
    int mb = lane * MPAD;

#define ML(o) lds[mb + (o)]

    for (int cc = wave; cc < 360; cc += 4) {
        if (!valid) continue;
        float v; int dest;

        if (cc < 5) {
            v = ML(cc);
            dest = a2 * OC + cc;
        } else if (cc < 20) {
            int l = cc - 5;
            int r = T2I[l], s = T2J[l];
            float acc = 0.f;
#pragma unroll
            for (int i = 0; i < 3; i++) acc += ML(5 + r*3 + i) * ML(5 + s*3 + i);
            v = acc;
            int f = l * NA + a2; int aa = f / 15; dest = aa * OC + 5 + (f - aa*15);
        } else if (cc < 35) {
            int l = cc - 20;
            int r = T2I[l], s = T2J[l];
            float acc = 0.f;
#pragma unroll
            for (int p = 0; p < 6; p++) acc += W2[p] * ML(20 + r*6 + p) * ML(20 + s*6 + p);
            v = acc;
            int f = l * NA + a2; int aa = f / 15; dest = aa * OC + 20 + (f - aa*15);
        } else if (cc < 50) {
            int l = cc - 35;
            int r = T2I[l], s = T2J[l];
            float acc = 0.f;
#pragma unroll
            for (int p = 0; p < 10; p++) acc += W3[p] * ML(50 + r*10 + p) * ML(50 + s*10 + p);
            v = acc;
            int f = l * NA + a2; int aa = f / 15; dest = aa * OC + 35 + (f - aa*15);
        } else if (cc < 85) {
            int l = cc - 50;
            int r = T3I[l], s = T3J[l], t = T3K[l];
            float R[6], S[6], T[6];
#pragma unroll
            for (int p = 0; p < 6; p++) { R[p]=ML(20+r*6+p); S[p]=ML(20+s*6+p); T[p]=ML(20+t*6+p); }
            float acc = 0.f;
#pragma unroll
            for (int i = 0; i < 3; i++)
#pragma unroll
            for (int j = 0; j < 3; j++)
#pragma unroll
            for (int k = 0; k < 3; k++)
                acc += R[P2[i*3+j]] * S[P2[i*3+k]] * T[P2[j*3+k]];
            v = acc;
            int f = l * NA + a2; int aa = f / 35; dest = aa * OC + 50 + (f - aa*35);
        } else if (cc < 160) {
            int l = cc - 85;
            int p = l / 5, t = l - p*5;
            int r = T2I[p], s = T2J[p];
            float T[6];
#pragma unroll
            for (int q = 0; q < 6; q++) T[q] = ML(20 + t*6 + q);
            float acc = 0.f;
#pragma unroll
            for (int i = 0; i < 3; i++)
#pragma unroll
            for (int j = 0; j < 3; j++)
                acc += ML(5 + r*3 + i) * ML(5 + s*3 + j) * T[P2[i*3+j]];
            v = acc;
            int f = l * NA + a2; int aa = f / 75; dest = aa * OC + 85 + (f - aa*75);
        } else if (cc < 235) {
            int l = cc - 160;
            int p = l / 5, t = l - p*5;
            int r = T2I[p], s = T2J[p];
            float R[10], S[10], T[6];
#pragma unroll
            for (int q = 0; q < 10; q++) { R[q]=ML(50+r*10+q); S[q]=ML(50+s*10+q); }
#pragma unroll
            for (int q = 0; q < 6;  q++) T[q] = ML(20 + t*6 + q);
            float acc = 0.f;
#pragma unroll
            for (int k = 0; k < 3; k++)
#pragma unroll
            for (int l2 = 0; l2 < 3; l2++) {
                float inner = 0.f;
#pragma unroll
                for (int i = 0; i < 3; i++)
#pragma unroll
                for (int j = 0; j < 3; j++)
                    inner += R[P3[(i*3+j)*3+k]] * S[P3[(i*3+j)*3+l2]];
                acc += inner * T[P2[k*3+l2]];
            }
            v = acc;
            int f = l * NA + a2; int aa = f / 75; dest = aa * OC + 160 + (f - aa*75);
        } else {
            int l = cc - 235;
            int r = l / 25; int rem = l - r*25; int s = rem / 5; int t = rem - s*5;
            float R[10], S[6], T1[3];
#pragma unroll
            for (int q = 0; q < 10; q++) R[q] = ML(50 + r*10 + q);
#pragma unroll
            for (int q = 0; q < 6;  q++) S[q] = ML(20 + s*6 + q);
#pragma unroll
            for (int q = 0; q < 3;  q++) T1[q] = ML(5 + t*3 + q);
            float acc = 0.f;
#pragma unroll
            for (int i = 0; i < 3; i++)
#pragma unroll
            for (int j = 0; j < 3; j++)
#pragma unroll
            for (int k = 0; k < 3; k++)
                acc += R[P3[(i*3+j)*3+k]] * S[P2[i*3+j]] * T1[k];
            v = acc;
            int f = l * NA + a2; int aa = f / 125; dest = aa * OC + 235 + (f - aa*125);
        }
        out[dest] = v;
    }
#undef ML
}

extern "C" void kernel_launch(void* const* d_in, const int* in_sizes, int n_in,
                              void* d_out, int out_size, void* d_ws, size_t ws_size,
                              hipStream_t stream) {
    const float* dr_vec = (const float*)d_in[0];
    const int*   Z      = (const int*)d_in[1];
    const int*   nbr    = (const int*)d_in[2];
    const float* coeffs = (const float*)d_in[3];
    float* out = (float*)d_out;

    // fast path layout: edgerec FIRST (32MB, 64B-aligned coalesced records) |
    // bins (11.2MB, 448B/atom = 64B-aligned) | cursor (100KB) | coeffsT (2.04MB)
    size_t edgerec_fl = (size_t)NE * 8;                       // floats
    size_t bins_i     = (size_t)NA * CAPI;                    // ints
    size_t need_fast  = edgerec_fl * sizeof(float)
                      + bins_i * sizeof(int)
                      + (size_t)NA * sizeof(int)
                      + (size_t)NS * NS * CROW * sizeof(float);

    if (ws_size >= need_fast) {
        float* edgerec = (float*)d_ws;
        int*   bins    = (int*)(edgerec + edgerec_fl);
        int*   cursor  = bins + bins_i;
        float* coeffsT = (float*)(cursor + NA);
        hipMemsetAsync(cursor, 0, (size_t)NA * sizeof(int), stream);
        const int TOT = NS * NS * (NR * NB);
        transpose_coeffs_kernel<<<(TOT + 255)/256, 256, 0, stream>>>(coeffs, coeffsT);
        edge_compute_kernel<<<(NE + 255)/256, 256, 0, stream>>>(dr_vec, Z, nbr, coeffsT, edgerec);
        id_scatter_kernel<<<(NE + 255)/256, 256, 0, stream>>>(nbr, cursor, bins);
        accum_contract_kernel<<<(NA + CHUNK - 1)/CHUNK, 256, 0, stream>>>(cursor, bins, edgerec, out);
    } else {
        // fallback: cursor[NA] | bins[NA*CAPI] | Mu[NA*MUS] (~21.3 MB)
        int*   cursor = (int*)d_ws;
        int*   bins   = cursor + NA;
        float* Mu     = (float*)(bins + bins_i);
        hipMemsetAsync(cursor, 0, (size_t)NA * sizeof(int), stream);
        scatter_kernel<<<(NE + 255)/256, 256, 0, stream>>>(nbr, cursor, bins);
        accum_kernel<<<(NA*8 + 255)/256, 256, 0, stream>>>(dr_vec, Z, nbr, coeffs, cursor, bins, Mu);
        contract_kernel<<<(NA + 63)/64, 256, 0, stream>>>(Mu, out);
    }
}

// Round 6
// 251.122 us; speedup vs baseline: 1.1751x; 1.1751x over previous
//
#include <hip/hip_runtime.h>
#include <math.h>

#define NR 5
#define NB 7
#define NS 119
#define NA 25000
#define NE 1000000
#define OC 360           // output columns per atom
#define MUS 100          // unique moment floats per atom
#define CAPI 112         // id bin capacity (fallback path only)
#define CHUNK 64         // atoms per accum/contract block (4 sub-lanes each, R4-proven)
#define MPAD 101         // LDS stride: gcd(101,32)=1 -> conflict-free
#define CROW 36          // padded coeffs row: 35 floats + 1 pad = 144B, float4-aligned

#define NB_BLK 256       // sort chunks
#define CH 3907          // edges per chunk (ceil(NE/NB_BLK))
#define NPAIR 12500      // NA/2 packed u16-pair counters (50KB LDS)

// tril index tables (wave-uniform index -> scalar loads)
static constexpr int T2I[15] = {0,1,1,2,2,2,3,3,3,3,4,4,4,4,4};
static constexpr int T2J[15] = {0,0,1,0,1,2,0,1,2,3,0,1,2,3,4};
static constexpr int T3I[35] = {0,1,1,1,2,2,2,2,2,2,3,3,3,3,3,3,3,3,3,3,4,4,4,4,4,4,4,4,4,4,4,4,4,4,4};
static constexpr int T3J[35] = {0,0,1,1,0,1,1,2,2,2,0,1,1,2,2,2,3,3,3,3,0,1,1,2,2,2,3,3,3,3,4,4,4,4,4};
static constexpr int T3K[35] = {0,0,0,1,0,0,1,0,1,2,0,0,1,0,1,2,0,1,2,3,0,0,1,0,1,2,0,1,2,3,0,1,2,3,4};

static constexpr int P2[9]  = {0,1,2, 1,3,4, 2,4,5};
static constexpr int P3[27] = {0,1,4, 1,2,5, 4,5,7,
                               1,2,5, 2,3,6, 5,6,8,
                               4,5,7, 5,6,8, 7,8,9};
static constexpr float W2[6]  = {1.f,2.f,2.f,1.f,2.f,1.f};
static constexpr float W3[10] = {1.f,3.f,3.f,1.f,3.f,6.f,3.f,3.f,3.f,1.f};

// ============================ FAST PATH ==================================
// R5 post-mortem: (a) random-gather accum = 150us -> accum MUST read dense
// contiguous bins; (b) 5-round invariance of edge_record at 74-95us across
// all traffic fixes + isolated id_scatter ~80us -> the 1M agent-scope
// atomics ARE the floor (~13 G atomics/s). This round: atomic-free counting
// sort (LDS histograms -> scan -> LDS-ranked scatter into exact dense bins).
// Counts per atom <=~96 -> all per-chunk/per-atom counters fit u16 (packed
// 2 per u32 in LDS; adds can't carry across the 16-bit boundary).

// pass 0: repack coeffs rows 35 -> 36 floats (144B, float4-aligned).
__global__ __launch_bounds__(256) void transpose_coeffs_kernel(
    const float* __restrict__ src, float* __restrict__ dst)
{
    int t = blockIdx.x * 256 + threadIdx.x;
    const int TOT = NS * NS * (NR * NB);
    if (t >= TOT) return;
    int pair = t / 35, rem = t - pair * 35;
    dst[pair * CROW + rem] = src[t];
}

// K1: per-chunk histogram over atoms, u16-packed in LDS. No global atomics.
__global__ __launch_bounds__(1024) void hist_kernel(
    const int* __restrict__ nbr, unsigned int* __restrict__ hist)
{
    __shared__ unsigned int h[NPAIR];
    int b = blockIdx.x;
    for (int i = threadIdx.x; i < NPAIR; i += 1024) h[i] = 0u;
    __syncthreads();
    int e0 = b * CH, e1 = min(NE, e0 + CH);
    for (int e = e0 + (int)threadIdx.x; e < e1; e += 1024) {
        int aj = nbr[NE + e];
        atomicAdd(&h[aj >> 1], 1u << ((aj & 1) * 16));
    }
    __syncthreads();
    unsigned int* out = hist + (size_t)b * NPAIR;
    for (int i = threadIdx.x; i < NPAIR; i += 1024) out[i] = h[i];
}

// K2a: column scan over chunks: partial[b][pair] = running prefix (packed),
// colsum[pair] = totals (packed). Coalesced: adjacent threads adjacent pairs.
__global__ __launch_bounds__(256) void colscan_kernel(
    const unsigned int* __restrict__ hist, unsigned int* __restrict__ partial,
    unsigned int* __restrict__ colsum)
{
    int t = blockIdx.x * 256 + threadIdx.x;
    if (t >= NPAIR) return;
    unsigned int run = 0u;
    for (int b = 0; b < NB_BLK; b++) {
        unsigned int v = hist[(size_t)b * NPAIR + t];
        partial[(size_t)b * NPAIR + t] = run;
        run += v;
    }
    colsum[t] = run;
}

// K2b: single-block exclusive scan over atoms -> base[a] (u32), base[NA]=NE.
__global__ __launch_bounds__(256) void basescan_kernel(
    const unsigned int* __restrict__ colsum, unsigned int* __restrict__ base)
{
    __shared__ unsigned int tot[256];
    int t = threadIdx.x;
    const int PPT = (NPAIR + 255) / 256;      // 49 pairs per thread
    int p0 = t * PPT, p1 = min(NPAIR, p0 + PPT);
    unsigned int s = 0u;
    for (int p = p0; p < p1; p++) {
        unsigned int v = colsum[p];
        s += (v & 0xFFFFu) + (v >> 16);
    }
    tot[t] = s;
    __syncthreads();
    for (int off = 1; off < 256; off <<= 1) {
        unsigned int v = (t >= off) ? tot[t - off] : 0u;
        __syncthreads();
        if (t >= off) tot[t] += v;
        __syncthreads();
    }
    unsigned int run = tot[t] - s;            // exclusive prefix for this thread
    for (int p = p0; p < p1; p++) {
        unsigned int v = colsum[p];
        base[2*p]     = run; run += (v & 0xFFFFu);
        base[2*p + 1] = run; run += (v >> 16);
    }
    if (t == 255) base[NA] = run;             // == NE
}

// K3: fused edge compute + DENSE sorted scatter. Rank via LDS fetch_add on
// counters pre-initialized to partial[b][*] (same packing -> direct copy).
// slot = base[aj] + rank. Zero global atomics; stores are fire-and-forget.
__global__ __launch_bounds__(1024) void sortscatter_kernel(
    const float* __restrict__ dr_vec, const int* __restrict__ Z,
    const int* __restrict__ nbr, const float* __restrict__ coeffsT,
    const unsigned int* __restrict__ partial, const unsigned int* __restrict__ base,
    float* __restrict__ binrec)
{
    __shared__ unsigned int ctr[NPAIR];
    int b = blockIdx.x;
    const unsigned int* prow = partial + (size_t)b * NPAIR;
    for (int i = threadIdx.x; i < NPAIR; i += 1024) ctr[i] = prow[i];
    __syncthreads();

    int e0 = b * CH, e1 = min(NE, e0 + CH);
    for (int e = e0 + (int)threadIdx.x; e < e1; e += 1024) {
        int aj = nbr[NE + e];
        int sh = (aj & 1) * 16;
        unsigned int old = atomicAdd(&ctr[aj >> 1], 1u << sh);
        unsigned int slot = base[aj] + ((old >> sh) & 0xFFFFu);

        int ai = nbr[e];
        float x = dr_vec[3*e+0], y = dr_vec[3*e+1], z = dr_vec[3*e+2];
        int Zi = Z[ai], Zj = Z[aj];

        const float4* c4 = (const float4*)(coeffsT + (size_t)(Zi*NS + Zj) * CROW);
        float4 cw[9];
#pragma unroll
        for (int k = 0; k < 9; k++) cw[k] = c4[k];
        const float* cf = (const float*)&cw[0];

        float dr  = sqrtf(x*x + y*y + z*z);
        float inv = 1.0f / (dr + 1e-5f);
        float d0 = x*inv, d1 = y*inv, d2 = z*inv;

        const float PI_F = 3.14159265358979323846f;
        const float betta = 49.0f / 36.0f;
        float rad_norm = powf(2.0f * betta / PI_F, 0.75f);
        float cut = (dr < 6.0f) ? 0.5f*(cosf(PI_F * dr * (1.0f/6.0f)) + 1.0f) : 0.0f;
        float scale = cut * 0.3779644730092272272f;   // 1/sqrt(7)

        float basis[NB];
#pragma unroll
        for (int q = 0; q < NB; q++) {
            float tt = dr - (float)q;
            basis[q] = rad_norm * expf(-betta * tt * tt);
        }

        float rad[NR];
#pragma unroll
        for (int r = 0; r < NR; r++) {
            float s = 0.f;
#pragma unroll
            for (int q = 0; q < NB; q++) s += basis[q] * cf[r*NB + q];
            rad[r] = s * scale;
        }

        float4* rp = (float4*)(binrec + (size_t)slot * 8);
        rp[0] = make_float4(rad[0], rad[1], rad[2], rad[3]);
        rp[1] = make_float4(rad[4], d0, d1, d2);
    }
}

// K4: accumulate + contract from DENSE bins [base[a], base[a+1]).
// Identical structure to the R4-proven kernel (CHUNK=64, 4 sub-lanes).
__global__ __launch_bounds__(256) void accum_contract_kernel(
    const unsigned int* __restrict__ base, const float* __restrict__ binrec,
    float* __restrict__ out)
{
    __shared__ float lds[CHUNK * MPAD];
    int bl = blockIdx.x * CHUNK;
    int nat  = min(CHUNK, NA - bl);

    int al  = threadIdx.x >> 2;          // local atom 0..63
    int sub = threadIdx.x & 3;
    int a   = bl + al;
    unsigned int b0 = 0u; int n = 0;
    if (a < NA) { b0 = base[a]; n = (int)(base[a+1] - b0); }

    float acc[MUS];
#pragma unroll
    for (int i = 0; i < MUS; i++) acc[i] = 0.f;

    const float* mybin = binrec + (size_t)b0 * 8;
    for (int p = sub; p < n; p += 4) {
        const float4* rp = (const float4*)(mybin + (size_t)p * 8);
        float4 r0 = rp[0], r1 = rp[1];
        float rad[NR] = {r0.x, r0.y, r0.z, r0.w, r1.x};
        float d0 = r1.y, d1 = r1.z, d2 = r1.w;

        float q2[6] = {d0*d0, d1*d0, d2*d0, d1*d1, d2*d1, d2*d2};
        float q3[10] = {d0*q2[0], d1*q2[0], d0*q2[3], d1*q2[3], d2*q2[0],
                        d2*q2[1], d2*q2[3], d0*q2[5], d1*q2[5], d2*q2[5]};

#pragma unroll
        for (int r = 0; r < NR; r++) {
            float rv = rad[r];
            acc[r] += rv;
            acc[5 + r*3 + 0] += rv*d0;
            acc[5 + r*3 + 1] += rv*d1;
            acc[5 + r*3 + 2] += rv*d2;
#pragma unroll
            for (int q = 0; q < 6; q++)  acc[20 + r*6  + q] += rv*q2[q];
#pragma unroll
            for (int q = 0; q < 10; q++) acc[50 + r*10 + q] += rv*q3[q];
        }
    }

    // reduce over 4 sub-lanes (within-wave groups), deposit into LDS tile
#pragma unroll
    for (int i = 0; i < MUS; i++) {
        float v = acc[i];
        v += __shfl_xor(v, 1, 64);
        v += __shfl_xor(v, 2, 64);
        if (sub == 0) lds[al * MPAD + i] = v;
    }
    __syncthreads();

    // ---- contract phase: lanes = atoms, waves split the 360 columns ----
    int wave = threadIdx.x >> 6, lane = threadIdx.x & 63;
    int a2 = bl + lane;
    bool valid = (lane < nat);
    int mb = lane * MPAD;

#define ML(o) lds[mb + (o)]

    for (int cc = wave; cc < 360; cc += 4) {
        if (!valid) continue;
        float v; int dest;

        if (cc < 5) {
            v = ML(cc);
            dest = a2 * OC + cc;
        } else if (cc < 20) {
            int l = cc - 5;
            int r = T2I[l], s = T2J[l];
            float acc2 = 0.f;
#pragma unroll
            for (int i = 0; i < 3; i++) acc2 += ML(5 + r*3 + i) * ML(5 + s*3 + i);
            v = acc2;
            int f = l * NA + a2; int aa = f / 15; dest = aa * OC + 5 + (f - aa*15);
        } else if (cc < 35) {
            int l = cc - 20;
            int r = T2I[l], s = T2J[l];
            float acc2 = 0.f;
#pragma unroll
            for (int p = 0; p < 6; p++) acc2 += W2[p] * ML(20 + r*6 + p) * ML(20 + s*6 + p);
            v = acc2;
            int f = l * NA + a2; int aa = f / 15; dest = aa * OC + 20 + (f - aa*15);
        } else if (cc < 50) {
            int l = cc - 35;
            int r = T2I[l], s = T2J[l];
            float acc2 = 0.f;
#pragma unroll
            for (int p = 0; p < 10; p++) acc2 += W3[p] * ML(50 + r*10 + p) * ML(50 + s*10 + p);
            v = acc2;
            int f = l * NA + a2; int aa = f / 15; dest = aa * OC + 35 + (f - aa*15);
        } else if (cc < 85) {
            int l = cc - 50;
            int r = T3I[l], s = T3J[l], t = T3K[l];
            float R[6], S[6], T[6];
#pragma unroll
            for (int p = 0; p < 6; p++) { R[p]=ML(20+r*6+p); S[p]=ML(20+s*6+p); T[p]=ML(20+t*6+p); }
            float acc2 = 0.f;
#pragma unroll
            for (int i = 0; i < 3; i++)
#pragma unroll
            for (int j = 0; j < 3; j++)
#pragma unroll
            for (int k = 0; k < 3; k++)
                acc2 += R[P2[i*3+j]] * S[P2[i*3+k]] * T[P2[j*3+k]];
            v = acc2;
            int f = l * NA + a2; int aa = f / 35; dest = aa * OC + 50 + (f - aa*35);
        } else if (cc < 160) {
            int l = cc - 85;
            int p = l / 5, t = l - p*5;
            int r = T2I[p], s = T2J[p];
            float T[6];
#pragma unroll
            for (int q = 0; q < 6; q++) T[q] = ML(20 + t*6 + q);
            float acc2 = 0.f;
#pragma unroll
            for (int i = 0; i < 3; i++)
#pragma unroll
            for (int j = 0; j < 3; j++)
                acc2 += ML(5 + r*3 + i) * ML(5 + s*3 + j) * T[P2[i*3+j]];
            v = acc2;
            int f = l * NA + a2; int aa = f / 75; dest = aa * OC + 85 + (f - aa*75);
        } else if (cc < 235) {
            int l = cc - 160;
            int p = l / 5, t = l - p*5;
            int r = T2I[p], s = T2J[p];
            float R[10], S[10], T[6];
#pragma unroll
            for (int q = 0; q < 10; q++) { R[q]=ML(50+r*10+q); S[q]=ML(50+s*10+q); }
#pragma unroll
            for (int q = 0; q < 6;  q++) T[q] = ML(20 + t*6 + q);
            float acc2 = 0.f;
#pragma unroll
            for (int k = 0; k < 3; k++)
#pragma unroll
            for (int l2 = 0; l2 < 3; l2++) {
                float inner = 0.f;
#pragma unroll
                for (int i = 0; i < 3; i++)
#pragma unroll
                for (int j = 0; j < 3; j++)
                    inner += R[P3[(i*3+j)*3+k]] * S[P3[(i*3+j)*3+l2]];
                acc2 += inner * T[P2[k*3+l2]];
            }
            v = acc2;
            int f = l * NA + a2; int aa = f / 75; dest = aa * OC + 160 + (f - aa*75);
        } else {
            int l = cc - 235;
            int r = l / 25; int rem = l - r*25; int s = rem / 5; int t = rem - s*5;
            float R[10], S[6], T1[3];
#pragma unroll
            for (int q = 0; q < 10; q++) R[q] = ML(50 + r*10 + q);
#pragma unroll
            for (int q = 0; q < 6;  q++) S[q] = ML(20 + s*6 + q);
#pragma unroll
            for (int q = 0; q < 3;  q++) T1[q] = ML(5 + t*3 + q);
            float acc2 = 0.f;
#pragma unroll
            for (int i = 0; i < 3; i++)
#pragma unroll
            for (int j = 0; j < 3; j++)
#pragma unroll
            for (int k = 0; k < 3; k++)
                acc2 += R[P3[(i*3+j)*3+k]] * S[P2[i*3+j]] * T1[k];
            v = acc2;
            int f = l * NA + a2; int aa = f / 125; dest = aa * OC + 235 + (f - aa*125);
        }
        out[dest] = v;
    }
#undef ML
}

// ========================= FALLBACK PATH =======================
__global__ __launch_bounds__(256) void scatter_kernel(
    const int* __restrict__ nbr, int* __restrict__ cursor, int* __restrict__ bins)
{
    int e = blockIdx.x * 256 + threadIdx.x;
    if (e >= NE) return;
    int aj = nbr[NE + e];
    int pos = __hip_atomic_fetch_add(&cursor[aj], 1, __ATOMIC_RELAXED, __HIP_MEMORY_SCOPE_AGENT);
    if (pos < CAPI) bins[(size_t)aj * CAPI + pos] = e;
}

__global__ __launch_bounds__(256) void accum_kernel(
    const float* __restrict__ dr_vec, const int* __restrict__ Z,
    const int* __restrict__ nbr, const float* __restrict__ coeffs,
    const int* __restrict__ cursor, const int* __restrict__ bins,
    float* __restrict__ Mu)
{
    __shared__ float red[32 * MUS];
    int t   = blockIdx.x * 256 + threadIdx.x;
    int a   = t >> 3;
    int sub = t & 7;
    int al  = threadIdx.x >> 3;
    int n   = (a < NA) ? min(cursor[a], CAPI) : 0;
    int Zj  = (a < NA) ? Z[a] : 0;

    float acc[MUS];
#pragma unroll
    for (int i = 0; i < MUS; i++) acc[i] = 0.f;

    const int* mybin = bins + (size_t)a * CAPI;
    const float PI_F = 3.14159265358979323846f;
    const float betta = 49.0f / 36.0f;
    float rad_norm = powf(2.0f * betta / PI_F, 0.75f);

    for (int p = sub; p < n; p += 8) {
        int e = mybin[p];
        float x = dr_vec[3*e+0], y = dr_vec[3*e+1], z = dr_vec[3*e+2];
        int Zi = Z[nbr[e]];

        float dr  = sqrtf(x*x + y*y + z*z);
        float inv = 1.0f / (dr + 1e-5f);
        float d0 = x*inv, d1 = y*inv, d2 = z*inv;

        float cut = (dr < 6.0f) ? 0.5f*(cosf(PI_F * dr * (1.0f/6.0f)) + 1.0f) : 0.0f;
        float scale = cut * 0.3779644730092272272f;

        float basis[NB];
#pragma unroll
        for (int b = 0; b < NB; b++) {
            float tt = dr - (float)b;
            basis[b] = rad_norm * expf(-betta * tt * tt);
        }

        const float* cp = coeffs + ((size_t)(Zi*NS + Zj)) * (NR*NB);
        float rad[NR];
#pragma unroll
        for (int r = 0; r < NR; r++) {
            float s = 0.f;
#pragma unroll
            for (int b = 0; b < NB; b++) s += basis[b] * cp[r*NB + b];
            rad[r] = s * scale;
        }

        float q2[6] = {d0*d0, d1*d0, d2*d0, d1*d1, d2*d1, d2*d2};
        float q3[10] = {d0*q2[0], d1*q2[0], d0*q2[3], d1*q2[3], d2*q2[0],
                        d2*q2[1], d2*q2[3], d0*q2[5], d1*q2[5], d2*q2[5]};

#pragma unroll
        for (int r = 0; r < NR; r++) {
            float rv = rad[r];
            acc[r] += rv;
            acc[5 + r*3 + 0] += rv*d0;
            acc[5 + r*3 + 1] += rv*d1;
            acc[5 + r*3 + 2] += rv*d2;
#pragma unroll
            for (int q = 0; q < 6; q++)  acc[20 + r*6  + q] += rv*q2[q];
#pragma unroll
            for (int q = 0; q < 10; q++) acc[50 + r*10 + q] += rv*q3[q];
        }
    }

#pragma unroll
    for (int i = 0; i < MUS; i++) {
        float v = acc[i];
        v += __shfl_xor(v, 1, 64);
        v += __shfl_xor(v, 2, 64);
        v += __shfl_xor(v, 4, 64);
        if (sub == 0) red[al * MUS + i] = v;
    }
    __syncthreads();

    for (int u = threadIdx.x; u < 32 * MUS; u += 256) {
        int ga = blockIdx.x * 32 + u / MUS;
        if (ga < NA) Mu[(size_t)ga * MUS + (u - (u / MUS) * MUS)] = red[u];
    }
}

__global__ __launch_bounds__(256) void contract_kernel(
    const float* __restrict__ Mu, float* __restrict__ out)
{
    __shared__ float lds[64 * MPAD];
    int base = blockIdx.x * 64;
    int nat  = min(64, NA - base);

    for (int t = threadIdx.x; t < nat * MUS; t += 256) {
        int al = t / MUS, off = t - al * MUS;
        lds[al * MPAD + off] = Mu[(size_t)base * MUS + t];
    }
    __syncthreads();

    int wave = threadIdx.x >> 6, lane = threadIdx.x & 63;
    int a2 = base + lane;
    bool valid = (lane < nat);
    int mb = lane * MPAD;

#define ML(o) lds[mb + (o)]

    for (int cc = wave; cc < 360; cc += 4) {
        if (!valid) continue;
        float v; int dest;

        if (cc < 5) {
            v = ML(cc);
            dest = a2 * OC + cc;
        } else if (cc < 20) {
            int l = cc - 5;
            int r = T2I[l], s = T2J[l];
            float acc = 0.f;
#pragma unroll
            for (int i = 0; i < 3; i++) acc += ML(5 + r*3 + i) * ML(5 + s*3 + i);
            v = acc;
            int f = l * NA + a2; int aa = f / 15; dest = aa * OC + 5 + (f - aa*15);
        } else if (cc < 35) {
            int l = cc - 20;
            int r = T2I[l], s = T2J[l];
            float acc = 0.f;
#pragma unroll
            for (int p = 0; p < 6; p++) acc += W2[p] * ML(20 + r*6 + p) * ML(20 + s*6 + p);
            v = acc;
            int f = l * NA + a2; int aa = f / 15; dest = aa * OC + 20 + (f - aa*15);
        } else if (cc < 50) {
            int l = cc - 35;
            int r = T2I[l], s = T2J[l];
            float acc = 0.f;
#pragma unroll
            for (int p = 0; p < 10; p++) acc += W3[p] * ML(50 + r*10 + p) * ML(50 + s*10 + p);
            v = acc;
            int f = l * NA + a2; int aa = f / 15; dest = aa * OC + 35 + (f - aa*15);
        } else if (cc < 85) {
            int l = cc - 50;
            int r = T3I[l], s = T3J[l], t = T3K[l];
            float R[6], S[6], T[6];
#pragma unroll
            for (int p = 0; p < 6; p++) { R[p]=ML(20+r*6+p); S[p]=ML(20+s*6+p); T[p]=ML(20+t*6+p); }
            float acc = 0.f;
#pragma unroll
            for (int i = 0; i < 3; i++)
#pragma unroll
            for (int j = 0; j < 3; j++)
#pragma unroll
            for (int k = 0; k < 3; k++)
                acc += R[P2[i*3+j]] * S[P2[i*3+k]] * T[P2[j*3+k]];
            v = acc;
            int f = l * NA + a2; int aa = f / 35; dest = aa * OC + 50 + (f - aa*35);
        } else if (cc < 160) {
            int l = cc - 85;
            int p = l / 5, t = l - p*5;
            int r = T2I[p], s = T2J[p];
            float T[6];
#pragma unroll
            for (int q = 0; q < 6; q++) T[q] = ML(20 + t*6 + q);
            float acc = 0.f;
#pragma unroll
            for (int i = 0; i < 3; i++)
#pragma unroll
            for (int j = 0; j < 3; j++)
                acc += ML(5 + r*3 + i) * ML(5 + s*3 + j) * T[P2[i*3+j]];
            v = acc;
            int f = l * NA + a2; int aa = f / 75; dest = aa * OC + 85 + (f - aa*75);
        } else if (cc < 235) {
            int l = cc - 160;
            int p = l / 5, t = l - p*5;
            int r = T2I[p], s = T2J[p];
            float R[10], S[10], T[6];
#pragma unroll
            for (int q = 0; q < 10; q++) { R[q]=ML(50+r*10+q); S[q]=ML(50+s*10+q); }
#pragma unroll
            for (int q = 0; q < 6;  q++) T[q] = ML(20 + t*6 + q);
            float acc = 0.f;
#pragma unroll
            for (int k = 0; k < 3; k++)
#pragma unroll
            for (int l2 = 0; l2 < 3; l2++) {
                float inner = 0.f;
#pragma unroll
                for (int i = 0; i < 3; i++)
#pragma unroll
                for (int j = 0; j < 3; j++)
                    inner += R[P3[(i*3+j)*3+k]] * S[P3[(i*3+j)*3+l2]];
                acc += inner * T[P2[k*3+l2]];
            }
            v = acc;
            int f = l * NA + a2; int aa = f / 75; dest = aa * OC + 160 + (f - aa*75);
        } else {
            int l = cc - 235;
            int r = l / 25; int rem = l - r*25; int s = rem / 5; int t = rem - s*5;
            float R[10], S[6], T1[3];
#pragma unroll
            for (int q = 0; q < 10; q++) R[q] = ML(50 + r*10 + q);
#pragma unroll
            for (int q = 0; q < 6;  q++) S[q] = ML(20 + s*6 + q);
#pragma unroll
            for (int q = 0; q < 3;  q++) T1[q] = ML(5 + t*3 + q);
            float acc = 0.f;
#pragma unroll
            for (int i = 0; i < 3; i++)
#pragma unroll
            for (int j = 0; j < 3; j++)
#pragma unroll
            for (int k = 0; k < 3; k++)
                acc += R[P3[(i*3+j)*3+k]] * S[P2[i*3+j]] * T1[k];
            v = acc;
            int f = l * NA + a2; int aa = f / 125; dest = aa * OC + 235 + (f - aa*125);
        }
        out[dest] = v;
    }
#undef ML
}

extern "C" void kernel_launch(void* const* d_in, const int* in_sizes, int n_in,
                              void* d_out, int out_size, void* d_ws, size_t ws_size,
                              hipStream_t stream) {
    const float* dr_vec = (const float*)d_in[0];
    const int*   Z      = (const int*)d_in[1];
    const int*   nbr    = (const int*)d_in[2];
    const float* coeffs = (const float*)d_in[3];
    float* out = (float*)d_out;

    // fast path layout (all 256B-aligned):
    // binrec 32MB | hist 12.8MB | partial 12.8MB | colsum 50KB | base 100KB | coeffsT 2.05MB
    auto aup = [](size_t x) { return (x + 255) & ~(size_t)255; };
    size_t off_binrec  = 0;
    size_t off_hist    = aup(off_binrec + (size_t)NE * 8 * sizeof(float));
    size_t off_partial = aup(off_hist + (size_t)NB_BLK * NPAIR * sizeof(unsigned int));
    size_t off_colsum  = aup(off_partial + (size_t)NB_BLK * NPAIR * sizeof(unsigned int));
    size_t off_base    = aup(off_colsum + (size_t)NPAIR * sizeof(unsigned int));
    size_t off_coefT   = aup(off_base + (size_t)(NA + 1) * sizeof(unsigned int));
    size_t need_fast   = off_coefT + (size_t)NS * NS * CROW * sizeof(float);

    if (ws_size >= need_fast) {
        char* w = (char*)d_ws;
        float*        binrec  = (float*)(w + off_binrec);
        unsigned int* hist    = (unsigned int*)(w + off_hist);
        unsigned int* partial = (unsigned int*)(w + off_partial);
        unsigned int* colsum  = (unsigned int*)(w + off_colsum);
        unsigned int* base    = (unsigned int*)(w + off_base);
        float*        coeffsT = (float*)(w + off_coefT);

        const int TOT = NS * NS * (NR * NB);
        transpose_coeffs_kernel<<<(TOT + 255)/256, 256, 0, stream>>>(coeffs, coeffsT);
        hist_kernel<<<NB_BLK, 1024, 0, stream>>>(nbr, hist);
        colscan_kernel<<<(NPAIR + 255)/256, 256, 0, stream>>>(hist, partial, colsum);
        basescan_kernel<<<1, 256, 0, stream>>>(colsum, base);
        sortscatter_kernel<<<NB_BLK, 1024, 0, stream>>>(dr_vec, Z, nbr, coeffsT, partial, base, binrec);
        accum_contract_kernel<<<(NA + CHUNK - 1)/CHUNK, 256, 0, stream>>>(base, binrec, out);
    } else {
        // fallback: cursor[NA] | bins[NA*CAPI] | Mu[NA*MUS] (~21.3 MB)
        int*   cursor = (int*)d_ws;
        int*   bins   = cursor + NA;
        float* Mu     = (float*)(bins + (size_t)NA * CAPI);
        hipMemsetAsync(cursor, 0, (size_t)NA * sizeof(int), stream);
        scatter_kernel<<<(NE + 255)/256, 256, 0, stream>>>(nbr, cursor, bins);
        accum_kernel<<<(NA*8 + 255)/256, 256, 0, stream>>>(dr_vec, Z, nbr, coeffs, cursor, bins, Mu);
        contract_kernel<<<(NA + 63)/64, 256, 0, stream>>>(Mu, out);
    }
}

// Round 7
// 245.646 us; speedup vs baseline: 1.2013x; 1.0223x over previous
//
#include <hip/hip_runtime.h>
#include <math.h>

#define NR 5
#define NB 7
#define NS 119
#define NA 25000
#define NE 1000000
#define OC 360           // output columns per atom
#define MUS 100          // unique moment floats per atom
#define CAPI 112         // id bin capacity (fallback path only)
#define CHUNK 64         // atoms per accum/contract block
#define MPAD 101         // LDS stride: gcd(101,32)=1 -> conflict-free
#define CROW 36          // padded coeffs row: 35 floats + 1 pad = 144B, float4-aligned

#define NB_BLK 256       // sort chunks
#define CH 3907          // edges per chunk (ceil(NE/NB_BLK))
#define NPAIR 12500      // NA/2 packed u16-pair counters (50KB LDS in hist)

// tril index tables (wave-uniform index -> scalar loads)
static constexpr int T2I[15] = {0,1,1,2,2,2,3,3,3,3,4,4,4,4,4};
static constexpr int T2J[15] = {0,0,1,0,1,2,0,1,2,3,0,1,2,3,4};
static constexpr int T3I[35] = {0,1,1,1,2,2,2,2,2,2,3,3,3,3,3,3,3,3,3,3,4,4,4,4,4,4,4,4,4,4,4,4,4,4,4};
static constexpr int T3J[35] = {0,0,1,1,0,1,1,2,2,2,0,1,1,2,2,2,3,3,3,3,0,1,1,2,2,2,3,3,3,3,4,4,4,4,4};
static constexpr int T3K[35] = {0,0,0,1,0,0,1,0,1,2,0,0,1,0,1,2,0,1,2,3,0,0,1,0,1,2,0,1,2,3,0,1,2,3,4};

static constexpr int P2[9]  = {0,1,2, 1,3,4, 2,4,5};
static constexpr int P3[27] = {0,1,4, 1,2,5, 4,5,7,
                               1,2,5, 2,3,6, 5,6,8,
                               4,5,7, 5,6,8, 7,8,9};
static constexpr float W2[6]  = {1.f,2.f,2.f,1.f,2.f,1.f};
static constexpr float W3[10] = {1.f,3.f,3.f,1.f,3.f,6.f,3.f,3.f,3.f,1.f};

// ============================ FAST PATH ==================================
// R6 post-mortem: sort structure works (dense bins, exact) but every pass
// was wave-starved: sortscatter 20% occ (50KB LDS, 256x1024 grid), accum 14%
// occ (391x4 waves), colscan 49 blocks x serial loads. This round keeps the
// pipeline and fixes GEOMETRY: rank captured in hist (u16/edge) ->
// sortscatter needs no LDS (256-thread blocks, 3907 blocks, full TLP);
// colscan batch-8 MLP; accum 8 sub-lanes + explicit record prefetch.

// pass 0: repack coeffs rows 35 -> 36 floats (144B, float4-aligned).
__global__ __launch_bounds__(256) void transpose_coeffs_kernel(
    const float* __restrict__ src, float* __restrict__ dst)
{
    int t = blockIdx.x * 256 + threadIdx.x;
    const int TOT = NS * NS * (NR * NB);
    if (t >= TOT) return;
    int pair = t / 35, rem = t - pair * 35;
    dst[pair * CROW + rem] = src[t];
}

// K1: per-chunk histogram + per-edge within-chunk rank (from LDS atomic).
__global__ __launch_bounds__(1024) void hist_kernel(
    const int* __restrict__ nbr, unsigned int* __restrict__ hist,
    unsigned short* __restrict__ rank)
{
    __shared__ unsigned int h[NPAIR];
    int b = blockIdx.x;
    for (int i = threadIdx.x; i < NPAIR; i += 1024) h[i] = 0u;
    __syncthreads();
    int e0 = b * CH, e1 = min(NE, e0 + CH);
    for (int e = e0 + (int)threadIdx.x; e < e1; e += 1024) {
        int aj = nbr[NE + e];
        int sh = (aj & 1) * 16;
        unsigned int old = atomicAdd(&h[aj >> 1], 1u << sh);
        rank[e] = (unsigned short)((old >> sh) & 0xFFFFu);
    }
    __syncthreads();
    unsigned int* out = hist + (size_t)b * NPAIR;
    for (int i = threadIdx.x; i < NPAIR; i += 1024) out[i] = h[i];
}

// K2a: column scan over chunks with batch-8 loads (8x MLP per thread).
__global__ __launch_bounds__(256) void colscan_kernel(
    const unsigned int* __restrict__ hist, unsigned int* __restrict__ partial,
    unsigned int* __restrict__ colsum)
{
    int t = blockIdx.x * 256 + threadIdx.x;
    if (t >= NPAIR) return;
    unsigned int run = 0u;
    for (int b0 = 0; b0 < NB_BLK; b0 += 8) {
        unsigned int v[8];
#pragma unroll
        for (int i = 0; i < 8; i++) v[i] = hist[(size_t)(b0 + i) * NPAIR + t];
#pragma unroll
        for (int i = 0; i < 8; i++) {
            partial[(size_t)(b0 + i) * NPAIR + t] = run;
            run += v[i];
        }
    }
    colsum[t] = run;
}

// K2b: single-block exclusive scan over atoms -> base[a] (u32), base[NA]=NE.
__global__ __launch_bounds__(256) void basescan_kernel(
    const unsigned int* __restrict__ colsum, unsigned int* __restrict__ base)
{
    __shared__ unsigned int tot[256];
    int t = threadIdx.x;
    const int PPT = (NPAIR + 255) / 256;      // 49 pairs per thread
    int p0 = t * PPT, p1 = min(NPAIR, p0 + PPT);
    unsigned int s = 0u;
    for (int p = p0; p < p1; p++) {
        unsigned int v = colsum[p];
        s += (v & 0xFFFFu) + (v >> 16);
    }
    tot[t] = s;
    __syncthreads();
    for (int off = 1; off < 256; off <<= 1) {
        unsigned int v = (t >= off) ? tot[t - off] : 0u;
        __syncthreads();
        if (t >= off) tot[t] += v;
        __syncthreads();
    }
    unsigned int run = tot[t] - s;            // exclusive prefix for this thread
    for (int p = p0; p < p1; p++) {
        unsigned int v = colsum[p];
        base[2*p]     = run; run += (v & 0xFFFFu);
        base[2*p + 1] = run; run += (v >> 16);
    }
    if (t == 255) base[NA] = run;             // == NE
}

// K3: fused edge compute + dense sorted scatter, NO LDS, full occupancy.
// slot = base[aj] + partial[b][aj] + rank[e]; partial/base are L2-resident
// small tables (12.8MB row-slice 50KB / 100KB). Fire-and-forget 32B stores.
__global__ __launch_bounds__(256) void sortscatter_kernel(
    const float* __restrict__ dr_vec, const int* __restrict__ Z,
    const int* __restrict__ nbr, const float* __restrict__ coeffsT,
    const unsigned int* __restrict__ partial, const unsigned int* __restrict__ base,
    const unsigned short* __restrict__ rank, float* __restrict__ binrec)
{
    int e = blockIdx.x * 256 + threadIdx.x;
    if (e >= NE) return;

    // slot chain issued first: nbr -> partial/base gathers overlap compute
    int aj = nbr[NE + e];
    int b  = e / CH;                          // chunk id (constant divisor)
    unsigned int pw = partial[(size_t)b * NPAIR + (aj >> 1)];
    unsigned int pr = (pw >> ((aj & 1) * 16)) & 0xFFFFu;
    unsigned int slot = base[aj] + pr + (unsigned int)rank[e];

    int ai = nbr[e];
    float x = dr_vec[3*e+0], y = dr_vec[3*e+1], z = dr_vec[3*e+2];
    int Zi = Z[ai], Zj = Z[aj];

    const float4* c4 = (const float4*)(coeffsT + (size_t)(Zi*NS + Zj) * CROW);
    float4 cw[9];
#pragma unroll
    for (int k = 0; k < 9; k++) cw[k] = c4[k];
    const float* cf = (const float*)&cw[0];

    float dr  = sqrtf(x*x + y*y + z*z);
    float inv = 1.0f / (dr + 1e-5f);
    float d0 = x*inv, d1 = y*inv, d2 = z*inv;

    const float PI_F = 3.14159265358979323846f;
    const float betta = 49.0f / 36.0f;
    float rad_norm = powf(2.0f * betta / PI_F, 0.75f);
    float cut = (dr < 6.0f) ? 0.5f*(cosf(PI_F * dr * (1.0f/6.0f)) + 1.0f) : 0.0f;
    float scale = cut * 0.3779644730092272272f;   // 1/sqrt(7)

    float basis[NB];
#pragma unroll
    for (int q = 0; q < NB; q++) {
        float tt = dr - (float)q;
        basis[q] = rad_norm * expf(-betta * tt * tt);
    }

    float rad[NR];
#pragma unroll
    for (int r = 0; r < NR; r++) {
        float s = 0.f;
#pragma unroll
        for (int q = 0; q < NB; q++) s += basis[q] * cf[r*NB + q];
        rad[r] = s * scale;
    }

    float4* rp = (float4*)(binrec + (size_t)slot * 8);
    rp[0] = make_float4(rad[0], rad[1], rad[2], rad[3]);
    rp[1] = make_float4(rad[4], d0, d1, d2);
}

// K4: accumulate + contract from dense bins [base[a], base[a+1]).
// 512 threads: 8 sub-lanes/atom (5 serial iters, 12 waves/CU) + explicit
// 1-deep record prefetch for load/compute overlap.
__global__ __launch_bounds__(512) void accum_contract_kernel(
    const unsigned int* __restrict__ base, const float* __restrict__ binrec,
    float* __restrict__ out)
{
    __shared__ float lds[CHUNK * MPAD];
    int bl = blockIdx.x * CHUNK;
    int nat  = min(CHUNK, NA - bl);

    int al  = threadIdx.x >> 3;          // local atom 0..63
    int sub = threadIdx.x & 7;
    int a   = bl + al;
    unsigned int b0 = 0u; int n = 0;
    if (a < NA) { b0 = base[a]; n = (int)(base[a+1] - b0); }

    float acc[MUS];
#pragma unroll
    for (int i = 0; i < MUS; i++) acc[i] = 0.f;

    const float* mybin = binrec + (size_t)b0 * 8;
    int p = sub;
    bool have = (p < n);
    float4 c0, c1;
    if (have) {
        const float4* rp = (const float4*)(mybin + (size_t)p * 8);
        c0 = rp[0]; c1 = rp[1];
    }
    while (have) {
        int pn = p + 8;
        bool hn = (pn < n);
        float4 n0, n1;
        if (hn) {                         // issue next loads before compute
            const float4* rp = (const float4*)(mybin + (size_t)pn * 8);
            n0 = rp[0]; n1 = rp[1];
        }
        float rad[NR] = {c0.x, c0.y, c0.z, c0.w, c1.x};
        float d0 = c1.y, d1 = c1.z, d2 = c1.w;

        float q2[6] = {d0*d0, d1*d0, d2*d0, d1*d1, d2*d1, d2*d2};
        float q3[10] = {d0*q2[0], d1*q2[0], d0*q2[3], d1*q2[3], d2*q2[0],
                        d2*q2[1], d2*q2[3], d0*q2[5], d1*q2[5], d2*q2[5]};

#pragma unroll
        for (int r = 0; r < NR; r++) {
            float rv = rad[r];
            acc[r] += rv;
            acc[5 + r*3 + 0] += rv*d0;
            acc[5 + r*3 + 1] += rv*d1;
            acc[5 + r*3 + 2] += rv*d2;
#pragma unroll
            for (int q = 0; q < 6; q++)  acc[20 + r*6  + q] += rv*q2[q];
#pragma unroll
            for (int q = 0; q < 10; q++) acc[50 + r*10 + q] += rv*q3[q];
        }
        c0 = n0; c1 = n1; p = pn; have = hn;
    }

    // reduce over 8 sub-lanes (within-wave groups), deposit into LDS tile
#pragma unroll
    for (int i = 0; i < MUS; i++) {
        float v = acc[i];
        v += __shfl_xor(v, 1, 64);
        v += __shfl_xor(v, 2, 64);
        v += __shfl_xor(v, 4, 64);
        if (sub == 0) lds[al * MPAD + i] = v;
    }
    __syncthreads();

    // ---- contract phase: lanes = atoms, 8 waves split the 360 columns ----
    int wave = threadIdx.x >> 6, lane = threadIdx.x & 63;
    int a2 = bl + lane;
    bool valid = (lane < nat);
    int mb = lane * MPAD;

#define ML(o) lds[mb + (o)]

    for (int cc = wave; cc < 360; cc += 8) {
        if (!valid) continue;
        float v; int dest;

        if (cc < 5) {
            v = ML(cc);
            dest = a2 * OC + cc;
        } else if (cc < 20) {
            int l = cc - 5;
            int r = T2I[l], s = T2J[l];
            float acc2 = 0.f;
#pragma unroll
            for (int i = 0; i < 3; i++) acc2 += ML(5 + r*3 + i) * ML(5 + s*3 + i);
            v = acc2;
            int f = l * NA + a2; int aa = f / 15; dest = aa * OC + 5 + (f - aa*15);
        } else if (cc < 35) {
            int l = cc - 20;
            int r = T2I[l], s = T2J[l];
            float acc2 = 0.f;
#pragma unroll
            for (int p2 = 0; p2 < 6; p2++) acc2 += W2[p2] * ML(20 + r*6 + p2) * ML(20 + s*6 + p2);
            v = acc2;
            int f = l * NA + a2; int aa = f / 15; dest = aa * OC + 20 + (f - aa*15);
        } else if (cc < 50) {
            int l = cc - 35;
            int r = T2I[l], s = T2J[l];
            float acc2 = 0.f;
#pragma unroll
            for (int p2 = 0; p2 < 10; p2++) acc2 += W3[p2] * ML(50 + r*10 + p2) * ML(50 + s*10 + p2);
            v = acc2;
            int f = l * NA + a2; int aa = f / 15; dest = aa * OC + 35 + (f - aa*15);
        } else if (cc < 85) {
            int l = cc - 50;
            int r = T3I[l], s = T3J[l], t = T3K[l];
            float R[6], S[6], T[6];
#pragma unroll
            for (int p2 = 0; p2 < 6; p2++) { R[p2]=ML(20+r*6+p2); S[p2]=ML(20+s*6+p2); T[p2]=ML(20+t*6+p2); }
            float acc2 = 0.f;
#pragma unroll
            for (int i = 0; i < 3; i++)
#pragma unroll
            for (int j = 0; j < 3; j++)
#pragma unroll
            for (int k = 0; k < 3; k++)
                acc2 += R[P2[i*3+j]] * S[P2[i*3+k]] * T[P2[j*3+k]];
            v = acc2;
            int f = l * NA + a2; int aa = f / 35; dest = aa * OC + 50 + (f - aa*35);
        } else if (cc < 160) {
            int l = cc - 85;
            int p2 = l / 5, t = l - p2*5;
            int r = T2I[p2], s = T2J[p2];
            float T[6];
#pragma unroll
            for (int q = 0; q < 6; q++) T[q] = ML(20 + t*6 + q);
            float acc2 = 0.f;
#pragma unroll
            for (int i = 0; i < 3; i++)
#pragma unroll
            for (int j = 0; j < 3; j++)
                acc2 += ML(5 + r*3 + i) * ML(5 + s*3 + j) * T[P2[i*3+j]];
            v = acc2;
            int f = l * NA + a2; int aa = f / 75; dest = aa * OC + 85 + (f - aa*75);
        } else if (cc < 235) {
            int l = cc - 160;
            int p2 = l / 5, t = l - p2*5;
            int r = T2I[p2], s = T2J[p2];
            float R[10], S[10], T[6];
#pragma unroll
            for (int q = 0; q < 10; q++) { R[q]=ML(50+r*10+q); S[q]=ML(50+s*10+q); }
#pragma unroll
            for (int q = 0; q < 6;  q++) T[q] = ML(20 + t*6 + q);
            float acc2 = 0.f;
#pragma unroll
            for (int k = 0; k < 3; k++)
#pragma unroll
            for (int l2 = 0; l2 < 3; l2++) {
                float inner = 0.f;
#pragma unroll
                for (int i = 0; i < 3; i++)
#pragma unroll
                for (int j = 0; j < 3; j++)
                    inner += R[P3[(i*3+j)*3+k]] * S[P3[(i*3+j)*3+l2]];
                acc2 += inner * T[P2[k*3+l2]];
            }
            v = acc2;
            int f = l * NA + a2; int aa = f / 75; dest = aa * OC + 160 + (f - aa*75);
        } else {
            int l = cc - 235;
            int r = l / 25; int rem = l - r*25; int s = rem / 5; int t = rem - s*5;
            float R[10], S[6], T1[3];
#pragma unroll
            for (int q = 0; q < 10; q++) R[q] = ML(50 + r*10 + q);
#pragma unroll
            for (int q = 0; q < 6;  q++) S[q] = ML(20 + s*6 + q);
#pragma unroll
            for (int q = 0; q < 3;  q++) T1[q] = ML(5 + t*3 + q);
            float acc2 = 0.f;
#pragma unroll
            for (int i = 0; i < 3; i++)
#pragma unroll
            for (int j = 0; j < 3; j++)
#pragma unroll
            for (int k = 0; k < 3; k++)
                acc2 += R[P3[(i*3+j)*3+k]] * S[P2[i*3+j]] * T1[k];
            v = acc2;
            int f = l * NA + a2; int aa = f / 125; dest = aa * OC + 235 + (f - aa*125);
        }
        out[dest] = v;
    }
#undef ML
}

// ========================= FALLBACK PATH =======================
__global__ __launch_bounds__(256) void scatter_kernel(
    const int* __restrict__ nbr, int* __restrict__ cursor, int* __restrict__ bins)
{
    int e = blockIdx.x * 256 + threadIdx.x;
    if (e >= NE) return;
    int aj = nbr[NE + e];
    int pos = __hip_atomic_fetch_add(&cursor[aj], 1, __ATOMIC_RELAXED, __HIP_MEMORY_SCOPE_AGENT);
    if (pos < CAPI) bins[(size_t)aj * CAPI + pos] = e;
}

__global__ __launch_bounds__(256) void accum_kernel(
    const float* __restrict__ dr_vec, const int* __restrict__ Z,
    const int* __restrict__ nbr, const float* __restrict__ coeffs,
    const int* __restrict__ cursor, const int* __restrict__ bins,
    float* __restrict__ Mu)
{
    __shared__ float red[32 * MUS];
    int t   = blockIdx.x * 256 + threadIdx.x;
    int a   = t >> 3;
    int sub = t & 7;
    int al  = threadIdx.x >> 3;
    int n   = (a < NA) ? min(cursor[a], CAPI) : 0;
    int Zj  = (a < NA) ? Z[a] : 0;

    float acc[MUS];
#pragma unroll
    for (int i = 0; i < MUS; i++) acc[i] = 0.f;

    const int* mybin = bins + (size_t)a * CAPI;
    const float PI_F = 3.14159265358979323846f;
    const float betta = 49.0f / 36.0f;
    float rad_norm = powf(2.0f * betta / PI_F, 0.75f);

    for (int p = sub; p < n; p += 8) {
        int e = mybin[p];
        float x = dr_vec[3*e+0], y = dr_vec[3*e+1], z = dr_vec[3*e+2];
        int Zi = Z[nbr[e]];

        float dr  = sqrtf(x*x + y*y + z*z);
        float inv = 1.0f / (dr + 1e-5f);
        float d0 = x*inv, d1 = y*inv, d2 = z*inv;

        float cut = (dr < 6.0f) ? 0.5f*(cosf(PI_F * dr * (1.0f/6.0f)) + 1.0f) : 0.0f;
        float scale = cut * 0.3779644730092272272f;

        float basis[NB];
#pragma unroll
        for (int b = 0; b < NB; b++) {
            float tt = dr - (float)b;
            basis[b] = rad_norm * expf(-betta * tt * tt);
        }

        const float* cp = coeffs + ((size_t)(Zi*NS + Zj)) * (NR*NB);
        float rad[NR];
#pragma unroll
        for (int r = 0; r < NR; r++) {
            float s = 0.f;
#pragma unroll
            for (int b = 0; b < NB; b++) s += basis[b] * cp[r*NB + b];
            rad[r] = s * scale;
        }

        float q2[6] = {d0*d0, d1*d0, d2*d0, d1*d1, d2*d1, d2*d2};
        float q3[10] = {d0*q2[0], d1*q2[0], d0*q2[3], d1*q2[3], d2*q2[0],
                        d2*q2[1], d2*q2[3], d0*q2[5], d1*q2[5], d2*q2[5]};

#pragma unroll
        for (int r = 0; r < NR; r++) {
            float rv = rad[r];
            acc[r] += rv;
            acc[5 + r*3 + 0] += rv*d0;
            acc[5 + r*3 + 1] += rv*d1;
            acc[5 + r*3 + 2] += rv*d2;
#pragma unroll
            for (int q = 0; q < 6; q++)  acc[20 + r*6  + q] += rv*q2[q];
#pragma unroll
            for (int q = 0; q < 10; q++) acc[50 + r*10 + q] += rv*q3[q];
        }
    }

#pragma unroll
    for (int i = 0; i < MUS; i++) {
        float v = acc[i];
        v += __shfl_xor(v, 1, 64);
        v += __shfl_xor(v, 2, 64);
        v += __shfl_xor(v, 4, 64);
        if (sub == 0) red[al * MUS + i] = v;
    }
    __syncthreads();

    for (int u = threadIdx.x; u < 32 * MUS; u += 256) {
        int ga = blockIdx.x * 32 + u / MUS;
        if (ga < NA) Mu[(size_t)ga * MUS + (u - (u / MUS) * MUS)] = red[u];
    }
}

__global__ __launch_bounds__(256) void contract_kernel(
    const float* __restrict__ Mu, float* __restrict__ out)
{
    __shared__ float lds[64 * MPAD];
    int base = blockIdx.x * 64;
    int nat  = min(64, NA - base);

    for (int t = threadIdx.x; t < nat * MUS; t += 256) {
        int al = t / MUS, off = t - al * MUS;
        lds[al * MPAD + off] = Mu[(size_t)base * MUS + t];
    }
    __syncthreads();

    int wave = threadIdx.x >> 6, lane = threadIdx.x & 63;
    int a2 = base + lane;
    bool valid = (lane < nat);
    int mb = lane * MPAD;

#define ML(o) lds[mb + (o)]

    for (int cc = wave; cc < 360; cc += 4) {
        if (!valid) continue;
        float v; int dest;

        if (cc < 5) {
            v = ML(cc);
            dest = a2 * OC + cc;
        } else if (cc < 20) {
            int l = cc - 5;
            int r = T2I[l], s = T2J[l];
            float acc = 0.f;
#pragma unroll
            for (int i = 0; i < 3; i++) acc += ML(5 + r*3 + i) * ML(5 + s*3 + i);
            v = acc;
            int f = l * NA + a2; int aa = f / 15; dest = aa * OC + 5 + (f - aa*15);
        } else if (cc < 35) {
            int l = cc - 20;
            int r = T2I[l], s = T2J[l];
            float acc = 0.f;
#pragma unroll
            for (int p = 0; p < 6; p++) acc += W2[p] * ML(20 + r*6 + p) * ML(20 + s*6 + p);
            v = acc;
            int f = l * NA + a2; int aa = f / 15; dest = aa * OC + 20 + (f - aa*15);
        } else if (cc < 50) {
            int l = cc - 35;
            int r = T2I[l], s = T2J[l];
            float acc = 0.f;
#pragma unroll
            for (int p = 0; p < 10; p++) acc += W3[p] * ML(50 + r*10 + p) * ML(50 + s*10 + p);
            v = acc;
            int f = l * NA + a2; int aa = f / 15; dest = aa * OC + 35 + (f - aa*15);
        } else if (cc < 85) {
            int l = cc - 50;
            int r = T3I[l], s = T3J[l], t = T3K[l];
            float R[6], S[6], T[6];
#pragma unroll
            for (int p = 0; p < 6; p++) { R[p]=ML(20+r*6+p); S[p]=ML(20+s*6+p); T[p]=ML(20+t*6+p); }
            float acc = 0.f;
#pragma unroll
            for (int i = 0; i < 3; i++)
#pragma unroll
            for (int j = 0; j < 3; j++)
#pragma unroll
            for (int k = 0; k < 3; k++)
                acc += R[P2[i*3+j]] * S[P2[i*3+k]] * T[P2[j*3+k]];
            v = acc;
            int f = l * NA + a2; int aa = f / 35; dest = aa * OC + 50 + (f - aa*35);
        } else if (cc < 160) {
            int l = cc - 85;
            int p = l / 5, t = l - p*5;
            int r = T2I[p], s = T2J[p];
            float T[6];
#pragma unroll
            for (int q = 0; q < 6; q++) T[q] = ML(20 + t*6 + q);
            float acc = 0.f;
#pragma unroll
            for (int i = 0; i < 3; i++)
#pragma unroll
            for (int j = 0; j < 3; j++)
                acc += ML(5 + r*3 + i) * ML(5 + s*3 + j) * T[P2[i*3+j]];
            v = acc;
            int f = l * NA + a2; int aa = f / 75; dest = aa * OC + 85 + (f - aa*75);
        } else if (cc < 235) {
            int l = cc - 160;
            int p = l / 5, t = l - p*5;
            int r = T2I[p], s = T2J[p];
            float R[10], S[10], T[6];
#pragma unroll
            for (int q = 0; q < 10; q++) { R[q]=ML(50+r*10+q); S[q]=ML(50+s*10+q); }
#pragma unroll
            for (int q = 0; q < 6;  q++) T[q] = ML(20 + t*6 + q);
            float acc = 0.f;
#pragma unroll
            for (int k = 0; k < 3; k++)
#pragma unroll
            for (int l2 = 0; l2 < 3; l2++) {
                float inner = 0.f;
#pragma unroll
                for (int i = 0; i < 3; i++)
#pragma unroll
                for (int j = 0; j < 3; j++)
                    inner += R[P3[(i*3+j)*3+k]] * S[P3[(i*3+j)*3+l2]];
                acc += inner * T[P2[k*3+l2]];
            }
            v = acc;
            int f = l * NA + a2; int aa = f / 75; dest = aa * OC + 160 + (f - aa*75);
        } else {
            int l = cc - 235;
            int r = l / 25; int rem = l - r*25; int s = rem / 5; int t = rem - s*5;
            float R[10], S[6], T1[3];
#pragma unroll
            for (int q = 0; q < 10; q++) R[q] = ML(50 + r*10 + q);
#pragma unroll
            for (int q = 0; q < 6;  q++) S[q] = ML(20 + s*6 + q);
#pragma unroll
            for (int q = 0; q < 3;  q++) T1[q] = ML(5 + t*3 + q);
            float acc = 0.f;
#pragma unroll
            for (int i = 0; i < 3; i++)
#pragma unroll
            for (int j = 0; j < 3; j++)
#pragma unroll
            for (int k = 0; k < 3; k++)
                acc += R[P3[(i*3+j)*3+k]] * S[P2[i*3+j]] * T1[k];
            v = acc;
            int f = l * NA + a2; int aa = f / 125; dest = aa * OC + 235 + (f - aa*125);
        }
        out[dest] = v;
    }
#undef ML
}

extern "C" void kernel_launch(void* const* d_in, const int* in_sizes, int n_in,
                              void* d_out, int out_size, void* d_ws, size_t ws_size,
                              hipStream_t stream) {
    const float* dr_vec = (const float*)d_in[0];
    const int*   Z      = (const int*)d_in[1];
    const int*   nbr    = (const int*)d_in[2];
    const float* coeffs = (const float*)d_in[3];
    float* out = (float*)d_out;

    // fast path layout (all 256B-aligned): binrec 32MB | hist 12.8MB |
    // partial 12.8MB | colsum 50KB | base 100KB | coeffsT 2.05MB | rank 2MB
    auto aup = [](size_t x) { return (x + 255) & ~(size_t)255; };
    size_t off_binrec  = 0;
    size_t off_hist    = aup(off_binrec + (size_t)NE * 8 * sizeof(float));
    size_t off_partial = aup(off_hist + (size_t)NB_BLK * NPAIR * sizeof(unsigned int));
    size_t off_colsum  = aup(off_partial + (size_t)NB_BLK * NPAIR * sizeof(unsigned int));
    size_t off_base    = aup(off_colsum + (size_t)NPAIR * sizeof(unsigned int));
    size_t off_coefT   = aup(off_base + (size_t)(NA + 1) * sizeof(unsigned int));
    size_t off_rank    = aup(off_coefT + (size_t)NS * NS * CROW * sizeof(float));
    size_t need_fast   = off_rank + (size_t)NE * sizeof(unsigned short);

    if (ws_size >= need_fast) {
        char* w = (char*)d_ws;
        float*          binrec  = (float*)(w + off_binrec);
        unsigned int*   hist    = (unsigned int*)(w + off_hist);
        unsigned int*   partial = (unsigned int*)(w + off_partial);
        unsigned int*   colsum  = (unsigned int*)(w + off_colsum);
        unsigned int*   base    = (unsigned int*)(w + off_base);
        float*          coeffsT = (float*)(w + off_coefT);
        unsigned short* rank    = (unsigned short*)(w + off_rank);

        const int TOT = NS * NS * (NR * NB);
        transpose_coeffs_kernel<<<(TOT + 255)/256, 256, 0, stream>>>(coeffs, coeffsT);
        hist_kernel<<<NB_BLK, 1024, 0, stream>>>(nbr, hist, rank);
        colscan_kernel<<<(NPAIR + 255)/256, 256, 0, stream>>>(hist, partial, colsum);
        basescan_kernel<<<1, 256, 0, stream>>>(colsum, base);
        sortscatter_kernel<<<(NE + 255)/256, 256, 0, stream>>>(dr_vec, Z, nbr, coeffsT, partial, base, rank, binrec);
        accum_contract_kernel<<<(NA + CHUNK - 1)/CHUNK, 512, 0, stream>>>(base, binrec, out);
    } else {
        // fallback: cursor[NA] | bins[NA*CAPI] | Mu[NA*MUS] (~21.3 MB)
        int*   cursor = (int*)d_ws;
        int*   bins   = cursor + NA;
        float* Mu     = (float*)(bins + (size_t)NA * CAPI);
        hipMemsetAsync(cursor, 0, (size_t)NA * sizeof(int), stream);
        scatter_kernel<<<(NE + 255)/256, 256, 0, stream>>>(nbr, cursor, bins);
        accum_kernel<<<(NA*8 + 255)/256, 256, 0, stream>>>(dr_vec, Z, nbr, coeffs, cursor, bins, Mu);
        contract_kernel<<<(NA + 63)/64, 256, 0, stream>>>(Mu, out);
    }
}

// Round 9
// 197.174 us; speedup vs baseline: 1.4967x; 1.2458x over previous
//
#include <hip/hip_runtime.h>
#include <math.h>

#define NR 5
#define NB 7
#define NS 119
#define NA 25000
#define NE 1000000
#define OC 360           // output columns per atom
#define MUS 100          // unique moment floats per atom
#define CAPR 96          // record bin capacity (lambda=40, max ~68, overflow ~1e-15)
#define CAPI 112         // id bin capacity (fallback path)
#define CHUNK 64         // atoms per accum/contract block
#define MPAD 101         // LDS stride: gcd(101,32)=1 -> conflict-free

// tril index tables (wave-uniform index -> scalar loads)
static constexpr int T2I[15] = {0,1,1,2,2,2,3,3,3,3,4,4,4,4,4};
static constexpr int T2J[15] = {0,0,1,0,1,2,0,1,2,3,0,1,2,3,4};
static constexpr int T3I[35] = {0,1,1,1,2,2,2,2,2,2,3,3,3,3,3,3,3,3,3,3,4,4,4,4,4,4,4,4,4,4,4,4,4,4,4};
static constexpr int T3J[35] = {0,0,1,1,0,1,1,2,2,2,0,1,1,2,2,2,3,3,3,3,0,1,1,2,2,2,3,3,3,3,4,4,4,4,4};
static constexpr int T3K[35] = {0,0,0,1,0,0,1,0,1,2,0,0,1,0,1,2,0,1,2,3,0,0,1,0,1,2,0,1,2,3,0,1,2,3,4};

static constexpr int P2[9]  = {0,1,2, 1,3,4, 2,4,5};
static constexpr int P3[27] = {0,1,4, 1,2,5, 4,5,7,
                               1,2,5, 2,3,6, 5,6,8,
                               4,5,7, 5,6,8, 7,8,9};
static constexpr float W2[6]  = {1.f,2.f,2.f,1.f,2.f,1.f};
static constexpr float W3[10] = {1.f,3.f,3.f,1.f,3.f,6.f,3.f,3.f,3.f,1.f};

// moment m -> (rad index, product index). P[0]=1, P[1..3]=d, P[4..9]=q2, P[10..19]=q3
static constexpr int MR[100] = {
    0,1,2,3,4,
    0,0,0,1,1,1,2,2,2,3,3,3,4,4,4,
    0,0,0,0,0,0, 1,1,1,1,1,1, 2,2,2,2,2,2, 3,3,3,3,3,3, 4,4,4,4,4,4,
    0,0,0,0,0,0,0,0,0,0, 1,1,1,1,1,1,1,1,1,1, 2,2,2,2,2,2,2,2,2,2,
    3,3,3,3,3,3,3,3,3,3, 4,4,4,4,4,4,4,4,4,4};
static constexpr int MP[100] = {
    0,0,0,0,0,
    1,2,3,1,2,3,1,2,3,1,2,3,1,2,3,
    4,5,6,7,8,9, 4,5,6,7,8,9, 4,5,6,7,8,9, 4,5,6,7,8,9, 4,5,6,7,8,9,
    10,11,12,13,14,15,16,17,18,19, 10,11,12,13,14,15,16,17,18,19,
    10,11,12,13,14,15,16,17,18,19, 10,11,12,13,14,15,16,17,18,19,
    10,11,12,13,14,15,16,17,18,19};

template<int S>
__device__ __forceinline__ void accum25(float acc[25], const float rad[5], const float P[20])
{
#pragma unroll
    for (int i = 0; i < 25; i++)
        acc[i] += rad[MR[S*25 + i]] * P[MP[S*25 + i]];   // all indices compile-time
}

// ============================ FAST PATH ==================================
// R7 post-mortem: acc[100]/thread SPILLS (VGPR_Count=72 vs 100+ needed);
// all accum variants were also grid-starved (<=12 waves/CU). Pass-1 ledger:
// 70-95us under every structure -> revert to the measured-best R0 kernel
// (74us: scalar gather, atomic LAST, unpadded cursor, dense bins).
// Pass-2 rebuilt: 16 waves = 4 moment-slices x 4 record-subsets; 25
// accumulators/thread (no spill), ~24 waves/CU, ordered LDS merge.
// (R8 run failed on infra, not kernel: barriers are uniform, LDS 25.9KB,
// launch_bounds(1024) caps VGPR at 128 -> launchable. Resubmitting.)

// pass 1: fused edge compute + record scatter (exact R0 structure).
__global__ __launch_bounds__(256) void edge_record_kernel(
    const float* __restrict__ dr_vec, const int* __restrict__ Z,
    const int* __restrict__ nbr, const float* __restrict__ coeffs,
    int* __restrict__ cursor, float* __restrict__ binrec)
{
    int e = blockIdx.x * 256 + threadIdx.x;
    if (e >= NE) return;
    float x = dr_vec[3*e+0], y = dr_vec[3*e+1], z = dr_vec[3*e+2];
    int ai = nbr[e];
    int aj = nbr[NE + e];
    int Zi = Z[ai], Zj = Z[aj];

    float dr  = sqrtf(x*x + y*y + z*z);
    float inv = 1.0f / (dr + 1e-5f);
    float d0 = x*inv, d1 = y*inv, d2 = z*inv;

    const float PI_F = 3.14159265358979323846f;
    const float betta = 49.0f / 36.0f;
    float rad_norm = powf(2.0f * betta / PI_F, 0.75f);
    float cut = (dr < 6.0f) ? 0.5f*(cosf(PI_F * dr * (1.0f/6.0f)) + 1.0f) : 0.0f;
    float scale = cut * 0.3779644730092272272f;   // 1/sqrt(7)

    float basis[NB];
#pragma unroll
    for (int b = 0; b < NB; b++) {
        float t = dr - (float)b;
        basis[b] = rad_norm * expf(-betta * t * t);
    }

    const float* cp = coeffs + ((size_t)(Zi*NS + Zj)) * (NR*NB);
    float rad[NR];
#pragma unroll
    for (int r = 0; r < NR; r++) {
        float s = 0.f;
#pragma unroll
        for (int b = 0; b < NB; b++) s += basis[b] * cp[r*NB + b];
        rad[r] = s * scale;
    }

    int pos = __hip_atomic_fetch_add(&cursor[aj], 1, __ATOMIC_RELAXED, __HIP_MEMORY_SCOPE_AGENT);
    if (pos < CAPR) {
        float4* rp = (float4*)(binrec + ((size_t)aj * CAPR + pos) * 8);
        rp[0] = make_float4(rad[0], rad[1], rad[2], rad[3]);
        rp[1] = make_float4(rad[4], d0, d1, d2);
    }
}

// pass 2: accumulate + contract. 1024 threads = 16 waves:
// wave = (sub, slice): slice owns 25 moments (wave-uniform, constant regs),
// sub strides records by 4. 391 blocks x 16 waves ~ 24 waves/CU.
__global__ __launch_bounds__(1024) void accum_contract_kernel(
    const int* __restrict__ cursor, const float* __restrict__ binrec,
    float* __restrict__ out)
{
    __shared__ float lds[CHUNK * MPAD];
    int bl  = blockIdx.x * CHUNK;
    int nat = min(CHUNK, NA - bl);

    int wave  = threadIdx.x >> 6;     // 0..15
    int lane  = threadIdx.x & 63;     // local atom
    int slice = wave & 3;             // moment slice (25 moments)
    int sub   = wave >> 2;            // record subset (stride 4)

    int a = bl + lane;
    int n = (a < NA) ? min(cursor[a], CAPR) : 0;

    float acc[25];
#pragma unroll
    for (int i = 0; i < 25; i++) acc[i] = 0.f;

    const float* mybin = binrec + (size_t)a * CAPR * 8;
    for (int p = sub; p < n; p += 4) {
        const float4* rp = (const float4*)(mybin + (size_t)p * 8);
        float4 r0 = rp[0], r1 = rp[1];
        float rad[5] = {r0.x, r0.y, r0.z, r0.w, r1.x};
        float d0 = r1.y, d1 = r1.z, d2 = r1.w;

        float P[20];
        P[0] = 1.f; P[1] = d0; P[2] = d1; P[3] = d2;
        P[4] = d0*d0; P[5] = d1*d0; P[6] = d2*d0;
        P[7] = d1*d1; P[8] = d2*d1; P[9] = d2*d2;
        P[10] = d0*P[4]; P[11] = d1*P[4]; P[12] = d0*P[7]; P[13] = d1*P[7];
        P[14] = d2*P[4]; P[15] = d2*P[5]; P[16] = d2*P[7]; P[17] = d0*P[9];
        P[18] = d1*P[9]; P[19] = d2*P[9];

        switch (slice) {              // wave-uniform: no divergence
            case 0: accum25<0>(acc, rad, P); break;
            case 1: accum25<1>(acc, rad, P); break;
            case 2: accum25<2>(acc, rad, P); break;
            default: accum25<3>(acc, rad, P); break;
        }
    }

    // merge the 4 record-subsets: ordered rounds, slices disjoint per round
    float* dst = &lds[lane * MPAD + slice * 25];
    for (int s = 0; s < 4; s++) {
        if (sub == s) {
            if (s == 0) {
#pragma unroll
                for (int i = 0; i < 25; i++) dst[i] = acc[i];
            } else {
#pragma unroll
                for (int i = 0; i < 25; i++) dst[i] += acc[i];
            }
        }
        __syncthreads();
    }

    // ---- contract phase: lanes = atoms, 16 waves split the 360 columns ----
    int a2 = bl + lane;
    bool valid = (lane < nat);
    int mb = lane * MPAD;

#define ML(o) lds[mb + (o)]

    for (int cc = wave; cc < 360; cc += 16) {
        if (!valid) continue;
        float v; int dest;

        if (cc < 5) {
            v = ML(cc);
            dest = a2 * OC + cc;
        } else if (cc < 20) {
            int l = cc - 5;
            int r = T2I[l], s = T2J[l];
            float acc2 = 0.f;
#pragma unroll
            for (int i = 0; i < 3; i++) acc2 += ML(5 + r*3 + i) * ML(5 + s*3 + i);
            v = acc2;
            int f = l * NA + a2; int aa = f / 15; dest = aa * OC + 5 + (f - aa*15);
        } else if (cc < 35) {
            int l = cc - 20;
            int r = T2I[l], s = T2J[l];
            float acc2 = 0.f;
#pragma unroll
            for (int p2 = 0; p2 < 6; p2++) acc2 += W2[p2] * ML(20 + r*6 + p2) * ML(20 + s*6 + p2);
            v = acc2;
            int f = l * NA + a2; int aa = f / 15; dest = aa * OC + 20 + (f - aa*15);
        } else if (cc < 50) {
            int l = cc - 35;
            int r = T2I[l], s = T2J[l];
            float acc2 = 0.f;
#pragma unroll
            for (int p2 = 0; p2 < 10; p2++) acc2 += W3[p2] * ML(50 + r*10 + p2) * ML(50 + s*10 + p2);
            v = acc2;
            int f = l * NA + a2; int aa = f / 15; dest = aa * OC + 35 + (f - aa*15);
        } else if (cc < 85) {
            int l = cc - 50;
            int r = T3I[l], s = T3J[l], t = T3K[l];
            float R[6], S[6], T[6];
#pragma unroll
            for (int p2 = 0; p2 < 6; p2++) { R[p2]=ML(20+r*6+p2); S[p2]=ML(20+s*6+p2); T[p2]=ML(20+t*6+p2); }
            float acc2 = 0.f;
#pragma unroll
            for (int i = 0; i < 3; i++)
#pragma unroll
            for (int j = 0; j < 3; j++)
#pragma unroll
            for (int k = 0; k < 3; k++)
                acc2 += R[P2[i*3+j]] * S[P2[i*3+k]] * T[P2[j*3+k]];
            v = acc2;
            int f = l * NA + a2; int aa = f / 35; dest = aa * OC + 50 + (f - aa*35);
        } else if (cc < 160) {
            int l = cc - 85;
            int p2 = l / 5, t = l - p2*5;
            int r = T2I[p2], s = T2J[p2];
            float T[6];
#pragma unroll
            for (int q = 0; q < 6; q++) T[q] = ML(20 + t*6 + q);
            float acc2 = 0.f;
#pragma unroll
            for (int i = 0; i < 3; i++)
#pragma unroll
            for (int j = 0; j < 3; j++)
                acc2 += ML(5 + r*3 + i) * ML(5 + s*3 + j) * T[P2[i*3+j]];
            v = acc2;
            int f = l * NA + a2; int aa = f / 75; dest = aa * OC + 85 + (f - aa*75);
        } else if (cc < 235) {
            int l = cc - 160;
            int p2 = l / 5, t = l - p2*5;
            int r = T2I[p2], s = T2J[p2];
            float R[10], S[10], T[6];
#pragma unroll
            for (int q = 0; q < 10; q++) { R[q]=ML(50+r*10+q); S[q]=ML(50+s*10+q); }
#pragma unroll
            for (int q = 0; q < 6;  q++) T[q] = ML(20 + t*6 + q);
            float acc2 = 0.f;
#pragma unroll
            for (int k = 0; k < 3; k++)
#pragma unroll
            for (int l2 = 0; l2 < 3; l2++) {
                float inner = 0.f;
#pragma unroll
                for (int i = 0; i < 3; i++)
#pragma unroll
                for (int j = 0; j < 3; j++)
                    inner += R[P3[(i*3+j)*3+k]] * S[P3[(i*3+j)*3+l2]];
                acc2 += inner * T[P2[k*3+l2]];
            }
            v = acc2;
            int f = l * NA + a2; int aa = f / 75; dest = aa * OC + 160 + (f - aa*75);
        } else {
            int l = cc - 235;
            int r = l / 25; int rem = l - r*25; int s = rem / 5; int t = rem - s*5;
            float R[10], S[6], T1[3];
#pragma unroll
            for (int q = 0; q < 10; q++) R[q] = ML(50 + r*10 + q);
#pragma unroll
            for (int q = 0; q < 6;  q++) S[q] = ML(20 + s*6 + q);
#pragma unroll
            for (int q = 0; q < 3;  q++) T1[q] = ML(5 + t*3 + q);
            float acc2 = 0.f;
#pragma unroll
            for (int i = 0; i < 3; i++)
#pragma unroll
            for (int j = 0; j < 3; j++)
#pragma unroll
            for (int k = 0; k < 3; k++)
                acc2 += R[P3[(i*3+j)*3+k]] * S[P2[i*3+j]] * T1[k];
            v = acc2;
            int f = l * NA + a2; int aa = f / 125; dest = aa * OC + 235 + (f - aa*125);
        }
        out[dest] = v;
    }
#undef ML
}

// ========================= FALLBACK PATH =======================
__global__ __launch_bounds__(256) void scatter_kernel(
    const int* __restrict__ nbr, int* __restrict__ cursor, int* __restrict__ bins)
{
    int e = blockIdx.x * 256 + threadIdx.x;
    if (e >= NE) return;
    int aj = nbr[NE + e];
    int pos = __hip_atomic_fetch_add(&cursor[aj], 1, __ATOMIC_RELAXED, __HIP_MEMORY_SCOPE_AGENT);
    if (pos < CAPI) bins[(size_t)aj * CAPI + pos] = e;
}

__global__ __launch_bounds__(256) void accum_kernel(
    const float* __restrict__ dr_vec, const int* __restrict__ Z,
    const int* __restrict__ nbr, const float* __restrict__ coeffs,
    const int* __restrict__ cursor, const int* __restrict__ bins,
    float* __restrict__ Mu)
{
    __shared__ float red[32 * MUS];
    int t   = blockIdx.x * 256 + threadIdx.x;
    int a   = t >> 3;
    int sub = t & 7;
    int al  = threadIdx.x >> 3;
    int n   = (a < NA) ? min(cursor[a], CAPI) : 0;
    int Zj  = (a < NA) ? Z[a] : 0;

    float acc[MUS];
#pragma unroll
    for (int i = 0; i < MUS; i++) acc[i] = 0.f;

    const int* mybin = bins + (size_t)a * CAPI;
    const float PI_F = 3.14159265358979323846f;
    const float betta = 49.0f / 36.0f;
    float rad_norm = powf(2.0f * betta / PI_F, 0.75f);

    for (int p = sub; p < n; p += 8) {
        int e = mybin[p];
        float x = dr_vec[3*e+0], y = dr_vec[3*e+1], z = dr_vec[3*e+2];
        int Zi = Z[nbr[e]];

        float dr  = sqrtf(x*x + y*y + z*z);
        float inv = 1.0f / (dr + 1e-5f);
        float d0 = x*inv, d1 = y*inv, d2 = z*inv;

        float cut = (dr < 6.0f) ? 0.5f*(cosf(PI_F * dr * (1.0f/6.0f)) + 1.0f) : 0.0f;
        float scale = cut * 0.3779644730092272272f;

        float basis[NB];
#pragma unroll
        for (int b = 0; b < NB; b++) {
            float tt = dr - (float)b;
            basis[b] = rad_norm * expf(-betta * tt * tt);
        }

        const float* cp = coeffs + ((size_t)(Zi*NS + Zj)) * (NR*NB);
        float rad[NR];
#pragma unroll
        for (int r = 0; r < NR; r++) {
            float s = 0.f;
#pragma unroll
            for (int b = 0; b < NB; b++) s += basis[b] * cp[r*NB + b];
            rad[r] = s * scale;
        }

        float q2[6] = {d0*d0, d1*d0, d2*d0, d1*d1, d2*d1, d2*d2};
        float q3[10] = {d0*q2[0], d1*q2[0], d0*q2[3], d1*q2[3], d2*q2[0],
                        d2*q2[1], d2*q2[3], d0*q2[5], d1*q2[5], d2*q2[5]};

#pragma unroll
        for (int r = 0; r < NR; r++) {
            float rv = rad[r];
            acc[r] += rv;
            acc[5 + r*3 + 0] += rv*d0;
            acc[5 + r*3 + 1] += rv*d1;
            acc[5 + r*3 + 2] += rv*d2;
#pragma unroll
            for (int q = 0; q < 6; q++)  acc[20 + r*6  + q] += rv*q2[q];
#pragma unroll
            for (int q = 0; q < 10; q++) acc[50 + r*10 + q] += rv*q3[q];
        }
    }

#pragma unroll
    for (int i = 0; i < MUS; i++) {
        float v = acc[i];
        v += __shfl_xor(v, 1, 64);
        v += __shfl_xor(v, 2, 64);
        v += __shfl_xor(v, 4, 64);
        if (sub == 0) red[al * MUS + i] = v;
    }
    __syncthreads();

    for (int u = threadIdx.x; u < 32 * MUS; u += 256) {
        int ga = blockIdx.x * 32 + u / MUS;
        if (ga < NA) Mu[(size_t)ga * MUS + (u - (u / MUS) * MUS)] = red[u];
    }
}

__global__ __launch_bounds__(256) void contract_kernel(
    const float* __restrict__ Mu, float* __restrict__ out)
{
    __shared__ float lds[64 * MPAD];
    int base = blockIdx.x * 64;
    int nat  = min(64, NA - base);

    for (int t = threadIdx.x; t < nat * MUS; t += 256) {
        int al = t / MUS, off = t - al * MUS;
        lds[al * MPAD + off] = Mu[(size_t)base * MUS + t];
    }
    __syncthreads();

    int wave = threadIdx.x >> 6, lane = threadIdx.x & 63;
    int a2 = base + lane;
    bool valid = (lane < nat);
    int mb = lane * MPAD;

#define ML(o) lds[mb + (o)]

    for (int cc = wave; cc < 360; cc += 4) {
        if (!valid) continue;
        float v; int dest;

        if (cc < 5) {
            v = ML(cc);
            dest = a2 * OC + cc;
        } else if (cc < 20) {
            int l = cc - 5;
            int r = T2I[l], s = T2J[l];
            float acc = 0.f;
#pragma unroll
            for (int i = 0; i < 3; i++) acc += ML(5 + r*3 + i) * ML(5 + s*3 + i);
            v = acc;
            int f = l * NA + a2; int aa = f / 15; dest = aa * OC + 5 + (f - aa*15);
        } else if (cc < 35) {
            int l = cc - 20;
            int r = T2I[l], s = T2J[l];
            float acc = 0.f;
#pragma unroll
            for (int p = 0; p < 6; p++) acc += W2[p] * ML(20 + r*6 + p) * ML(20 + s*6 + p);
            v = acc;
            int f = l * NA + a2; int aa = f / 15; dest = aa * OC + 20 + (f - aa*15);
        } else if (cc < 50) {
            int l = cc - 35;
            int r = T2I[l], s = T2J[l];
            float acc = 0.f;
#pragma unroll
            for (int p = 0; p < 10; p++) acc += W3[p] * ML(50 + r*10 + p) * ML(50 + s*10 + p);
            v = acc;
            int f = l * NA + a2; int aa = f / 15; dest = aa * OC + 35 + (f - aa*15);
        } else if (cc < 85) {
            int l = cc - 50;
            int r = T3I[l], s = T3J[l], t = T3K[l];
            float R[6], S[6], T[6];
#pragma unroll
            for (int p = 0; p < 6; p++) { R[p]=ML(20+r*6+p); S[p]=ML(20+s*6+p); T[p]=ML(20+t*6+p); }
            float acc = 0.f;
#pragma unroll
            for (int i = 0; i < 3; i++)
#pragma unroll
            for (int j = 0; j < 3; j++)
#pragma unroll
            for (int k = 0; k < 3; k++)
                acc += R[P2[i*3+j]] * S[P2[i*3+k]] * T[P2[j*3+k]];
            v = acc;
            int f = l * NA + a2; int aa = f / 35; dest = aa * OC + 50 + (f - aa*35);
        } else if (cc < 160) {
            int l = cc - 85;
            int p = l / 5, t = l - p*5;
            int r = T2I[p], s = T2J[p];
            float T[6];
#pragma unroll
            for (int q = 0; q < 6; q++) T[q] = ML(20 + t*6 + q);
            float acc = 0.f;
#pragma unroll
            for (int i = 0; i < 3; i++)
#pragma unroll
            for (int j = 0; j < 3; j++)
                acc += ML(5 + r*3 + i) * ML(5 + s*3 + j) * T[P2[i*3+j]];
            v = acc;
            int f = l * NA + a2; int aa = f / 75; dest = aa * OC + 85 + (f - aa*75);
        } else if (cc < 235) {
            int l = cc - 160;
            int p = l / 5, t = l - p*5;
            int r = T2I[p], s = T2J[p];
            float R[10], S[10], T[6];
#pragma unroll
            for (int q = 0; q < 10; q++) { R[q]=ML(50+r*10+q); S[q]=ML(50+s*10+q); }
#pragma unroll
            for (int q = 0; q < 6;  q++) T[q] = ML(20 + t*6 + q);
            float acc = 0.f;
#pragma unroll
            for (int k = 0; k < 3; k++)
#pragma unroll
            for (int l2 = 0; l2 < 3; l2++) {
                float inner = 0.f;
#pragma unroll
                for (int i = 0; i < 3; i++)
#pragma unroll
                for (int j = 0; j < 3; j++)
                    inner += R[P3[(i*3+j)*3+k]] * S[P3[(i*3+j)*3+l2]];
                acc += inner * T[P2[k*3+l2]];
            }
            v = acc;
            int f = l * NA + a2; int aa = f / 75; dest = aa * OC + 160 + (f - aa*75);
        } else {
            int l = cc - 235;
            int r = l / 25; int rem = l - r*25; int s = rem / 5; int t = rem - s*5;
            float R[10], S[6], T1[3];
#pragma unroll
            for (int q = 0; q < 10; q++) R[q] = ML(50 + r*10 + q);
#pragma unroll
            for (int q = 0; q < 6;  q++) S[q] = ML(20 + s*6 + q);
#pragma unroll
            for (int q = 0; q < 3;  q++) T1[q] = ML(5 + t*3 + q);
            float acc = 0.f;
#pragma unroll
            for (int i = 0; i < 3; i++)
#pragma unroll
            for (int j = 0; j < 3; j++)
#pragma unroll
            for (int k = 0; k < 3; k++)
                acc += R[P3[(i*3+j)*3+k]] * S[P2[i*3+j]] * T1[k];
            v = acc;
            int f = l * NA + a2; int aa = f / 125; dest = aa * OC + 235 + (f - aa*125);
        }
        out[dest] = v;
    }
#undef ML
}

extern "C" void kernel_launch(void* const* d_in, const int* in_sizes, int n_in,
                              void* d_out, int out_size, void* d_ws, size_t ws_size,
                              hipStream_t stream) {
    const float* dr_vec = (const float*)d_in[0];
    const int*   Z      = (const int*)d_in[1];
    const int*   nbr    = (const int*)d_in[2];
    const float* coeffs = (const float*)d_in[3];
    float* out = (float*)d_out;

    // fast path: binrec FIRST (76.8MB, 64B-aligned records), then cursor[NA]
    size_t binrec_fl = (size_t)NA * CAPR * 8;          // floats
    size_t need_fast = binrec_fl * sizeof(float) + (size_t)NA * sizeof(int);

    if (ws_size >= need_fast) {
        float* binrec = (float*)d_ws;
        int*   cursor = (int*)(binrec + binrec_fl);
        hipMemsetAsync(cursor, 0, (size_t)NA * sizeof(int), stream);
        edge_record_kernel<<<(NE + 255)/256, 256, 0, stream>>>(dr_vec, Z, nbr, coeffs, cursor, binrec);
        accum_contract_kernel<<<(NA + CHUNK - 1)/CHUNK, 1024, 0, stream>>>(cursor, binrec, out);
    } else {
        // fallback: cursor[NA] | bins[NA*CAPI] | Mu[NA*MUS] (~21.3 MB)
        int*   cursor = (int*)d_ws;
        int*   bins   = cursor + NA;
        float* Mu     = (float*)(bins + (size_t)NA * CAPI);
        hipMemsetAsync(cursor, 0, (size_t)NA * sizeof(int), stream);
        scatter_kernel<<<(NE + 255)/256, 256, 0, stream>>>(nbr, cursor, bins);
        accum_kernel<<<(NA*8 + 255)/256, 256, 0, stream>>>(dr_vec, Z, nbr, coeffs, cursor, bins, Mu);
        contract_kernel<<<(NA + 63)/64, 256, 0, stream>>>(Mu, out);
    }
}

// Round 10
// 192.922 us; speedup vs baseline: 1.5296x; 1.0220x over previous
//
#include <hip/hip_runtime.h>
#include <math.h>

#define NR 5
#define NB 7
#define NS 119
#define NA 25000
#define NE 1000000
#define OC 360           // output columns per atom
#define MUS 100          // unique moment floats per atom
#define CAPR 96          // record bin capacity (lambda=40, max ~68, overflow ~1e-15)
#define CAPI 112         // id bin capacity (fallback path)
#define CHUNK 64         // atoms per accum/contract block
#define MPAD 101         // LDS stride: gcd(101,32)=1 -> conflict-free

// tril index tables (wave-uniform index -> scalar loads)
static constexpr int T2I[15] = {0,1,1,2,2,2,3,3,3,3,4,4,4,4,4};
static constexpr int T2J[15] = {0,0,1,0,1,2,0,1,2,3,0,1,2,3,4};
static constexpr int T3I[35] = {0,1,1,1,2,2,2,2,2,2,3,3,3,3,3,3,3,3,3,3,4,4,4,4,4,4,4,4,4,4,4,4,4,4,4};
static constexpr int T3J[35] = {0,0,1,1,0,1,1,2,2,2,0,1,1,2,2,2,3,3,3,3,0,1,1,2,2,2,3,3,3,3,4,4,4,4,4};
static constexpr int T3K[35] = {0,0,0,1,0,0,1,0,1,2,0,0,1,0,1,2,0,1,2,3,0,0,1,0,1,2,0,1,2,3,0,1,2,3,4};

static constexpr int P2[9]  = {0,1,2, 1,3,4, 2,4,5};
static constexpr int P3[27] = {0,1,4, 1,2,5, 4,5,7,
                               1,2,5, 2,3,6, 5,6,8,
                               4,5,7, 5,6,8, 7,8,9};
static constexpr float W2[6]  = {1.f,2.f,2.f,1.f,2.f,1.f};
static constexpr float W3[10] = {1.f,3.f,3.f,1.f,3.f,6.f,3.f,3.f,3.f,1.f};

// moment m -> (rad index, product index). P[0]=1, P[1..3]=d, P[4..9]=q2, P[10..19]=q3
static constexpr int MR[100] = {
    0,1,2,3,4,
    0,0,0,1,1,1,2,2,2,3,3,3,4,4,4,
    0,0,0,0,0,0, 1,1,1,1,1,1, 2,2,2,2,2,2, 3,3,3,3,3,3, 4,4,4,4,4,4,
    0,0,0,0,0,0,0,0,0,0, 1,1,1,1,1,1,1,1,1,1, 2,2,2,2,2,2,2,2,2,2,
    3,3,3,3,3,3,3,3,3,3, 4,4,4,4,4,4,4,4,4,4};
static constexpr int MP[100] = {
    0,0,0,0,0,
    1,2,3,1,2,3,1,2,3,1,2,3,1,2,3,
    4,5,6,7,8,9, 4,5,6,7,8,9, 4,5,6,7,8,9, 4,5,6,7,8,9, 4,5,6,7,8,9,
    10,11,12,13,14,15,16,17,18,19, 10,11,12,13,14,15,16,17,18,19,
    10,11,12,13,14,15,16,17,18,19, 10,11,12,13,14,15,16,17,18,19,
    10,11,12,13,14,15,16,17,18,19};

template<int S>
__device__ __forceinline__ void accum25(float acc[25], const float rad[5], const float P[20])
{
#pragma unroll
    for (int i = 0; i < 25; i++)
        acc[i] += rad[MR[S*25 + i]] * P[MP[S*25 + i]];   // all indices compile-time
}

// ============================ FAST PATH ==================================
// R9: 197.2us best. edge_record stable at 75-76 (VGPR 28, WRITE 64.5MB =
// 64B/record line-touch, the random-line floor). accum dropped below top-5
// (<75us) with the no-spill 25-acc slicing. This round: (1) accum walks
// records in ADJACENT PAIRS so each 64B bin line is touched once (2nd read
// is L1-hit) -> L2/L3 line touches halve; (2) powf constant-folded.

// pass 1: fused edge compute + record scatter (R0 structure, measured 74-76us).
__global__ __launch_bounds__(256) void edge_record_kernel(
    const float* __restrict__ dr_vec, const int* __restrict__ Z,
    const int* __restrict__ nbr, const float* __restrict__ coeffs,
    int* __restrict__ cursor, float* __restrict__ binrec)
{
    int e = blockIdx.x * 256 + threadIdx.x;
    if (e >= NE) return;
    float x = dr_vec[3*e+0], y = dr_vec[3*e+1], z = dr_vec[3*e+2];
    int ai = nbr[e];
    int aj = nbr[NE + e];
    int Zi = Z[ai], Zj = Z[aj];

    float dr  = sqrtf(x*x + y*y + z*z);
    float inv = 1.0f / (dr + 1e-5f);
    float d0 = x*inv, d1 = y*inv, d2 = z*inv;

    const float PI_F = 3.14159265358979323846f;
    const float betta = 49.0f / 36.0f;
    const float rad_norm = 0.89812905f;          // (2*betta/pi)^0.75, folded
    float cut = (dr < 6.0f) ? 0.5f*(cosf(PI_F * dr * (1.0f/6.0f)) + 1.0f) : 0.0f;
    float scale = cut * 0.3779644730092272272f * rad_norm;   // cut/sqrt(7)*norm

    float basis[NB];
#pragma unroll
    for (int b = 0; b < NB; b++) {
        float t = dr - (float)b;
        basis[b] = expf(-betta * t * t);
    }

    const float* cp = coeffs + ((size_t)(Zi*NS + Zj)) * (NR*NB);
    float rad[NR];
#pragma unroll
    for (int r = 0; r < NR; r++) {
        float s = 0.f;
#pragma unroll
        for (int b = 0; b < NB; b++) s += basis[b] * cp[r*NB + b];
        rad[r] = s * scale;
    }

    int pos = __hip_atomic_fetch_add(&cursor[aj], 1, __ATOMIC_RELAXED, __HIP_MEMORY_SCOPE_AGENT);
    if (pos < CAPR) {
        float4* rp = (float4*)(binrec + ((size_t)aj * CAPR + pos) * 8);
        rp[0] = make_float4(rad[0], rad[1], rad[2], rad[3]);
        rp[1] = make_float4(rad[4], d0, d1, d2);
    }
}

// pass 2: accumulate + contract. 1024 threads = 16 waves:
// wave = (sub, slice): slice owns 25 moments (wave-uniform, constant regs),
// sub owns record-pairs {2s,2s+1, 2s+8,2s+9, ...} -> one 64B line per pair,
// second record L1-hit. 391 blocks x 16 waves.
__global__ __launch_bounds__(1024) void accum_contract_kernel(
    const int* __restrict__ cursor, const float* __restrict__ binrec,
    float* __restrict__ out)
{
    __shared__ float lds[CHUNK * MPAD];
    int bl  = blockIdx.x * CHUNK;
    int nat = min(CHUNK, NA - bl);

    int wave  = threadIdx.x >> 6;     // 0..15
    int lane  = threadIdx.x & 63;     // local atom
    int slice = wave & 3;             // moment slice (25 moments)
    int sub   = wave >> 2;            // record-pair subset

    int a = bl + lane;
    int n = (a < NA) ? min(cursor[a], CAPR) : 0;

    float acc[25];
#pragma unroll
    for (int i = 0; i < 25; i++) acc[i] = 0.f;

    const float* mybin = binrec + (size_t)a * CAPR * 8;
    for (int pp = sub * 2; pp < n; pp += 8) {
        int pend = min(pp + 2, n);
        for (int p = pp; p < pend; p++) {     // 2nd iter hits the same 64B line
            const float4* rp = (const float4*)(mybin + (size_t)p * 8);
            float4 r0 = rp[0], r1 = rp[1];
            float rad[5] = {r0.x, r0.y, r0.z, r0.w, r1.x};
            float d0 = r1.y, d1 = r1.z, d2 = r1.w;

            float P[20];
            P[0] = 1.f; P[1] = d0; P[2] = d1; P[3] = d2;
            P[4] = d0*d0; P[5] = d1*d0; P[6] = d2*d0;
            P[7] = d1*d1; P[8] = d2*d1; P[9] = d2*d2;
            P[10] = d0*P[4]; P[11] = d1*P[4]; P[12] = d0*P[7]; P[13] = d1*P[7];
            P[14] = d2*P[4]; P[15] = d2*P[5]; P[16] = d2*P[7]; P[17] = d0*P[9];
            P[18] = d1*P[9]; P[19] = d2*P[9];

            switch (slice) {          // wave-uniform: no divergence
                case 0: accum25<0>(acc, rad, P); break;
                case 1: accum25<1>(acc, rad, P); break;
                case 2: accum25<2>(acc, rad, P); break;
                default: accum25<3>(acc, rad, P); break;
            }
        }
    }

    // merge the 4 record-subsets: ordered rounds, slices disjoint per round
    float* dst = &lds[lane * MPAD + slice * 25];
    for (int s = 0; s < 4; s++) {
        if (sub == s) {
            if (s == 0) {
#pragma unroll
                for (int i = 0; i < 25; i++) dst[i] = acc[i];
            } else {
#pragma unroll
                for (int i = 0; i < 25; i++) dst[i] += acc[i];
            }
        }
        __syncthreads();
    }

    // ---- contract phase: lanes = atoms, 16 waves split the 360 columns ----
    int a2 = bl + lane;
    bool valid = (lane < nat);
    int mb = lane * MPAD;

#define ML(o) lds[mb + (o)]

    for (int cc = wave; cc < 360; cc += 16) {
        if (!valid) continue;
        float v; int dest;

        if (cc < 5) {
            v = ML(cc);
            dest = a2 * OC + cc;
        } else if (cc < 20) {
            int l = cc - 5;
            int r = T2I[l], s = T2J[l];
            float acc2 = 0.f;
#pragma unroll
            for (int i = 0; i < 3; i++) acc2 += ML(5 + r*3 + i) * ML(5 + s*3 + i);
            v = acc2;
            int f = l * NA + a2; int aa = f / 15; dest = aa * OC + 5 + (f - aa*15);
        } else if (cc < 35) {
            int l = cc - 20;
            int r = T2I[l], s = T2J[l];
            float acc2 = 0.f;
#pragma unroll
            for (int p2 = 0; p2 < 6; p2++) acc2 += W2[p2] * ML(20 + r*6 + p2) * ML(20 + s*6 + p2);
            v = acc2;
            int f = l * NA + a2; int aa = f / 15; dest = aa * OC + 20 + (f - aa*15);
        } else if (cc < 50) {
            int l = cc - 35;
            int r = T2I[l], s = T2J[l];
            float acc2 = 0.f;
#pragma unroll
            for (int p2 = 0; p2 < 10; p2++) acc2 += W3[p2] * ML(50 + r*10 + p2) * ML(50 + s*10 + p2);
            v = acc2;
            int f = l * NA + a2; int aa = f / 15; dest = aa * OC + 35 + (f - aa*15);
        } else if (cc < 85) {
            int l = cc - 50;
            int r = T3I[l], s = T3J[l], t = T3K[l];
            float R[6], S[6], T[6];
#pragma unroll
            for (int p2 = 0; p2 < 6; p2++) { R[p2]=ML(20+r*6+p2); S[p2]=ML(20+s*6+p2); T[p2]=ML(20+t*6+p2); }
            float acc2 = 0.f;
#pragma unroll
            for (int i = 0; i < 3; i++)
#pragma unroll
            for (int j = 0; j < 3; j++)
#pragma unroll
            for (int k = 0; k < 3; k++)
                acc2 += R[P2[i*3+j]] * S[P2[i*3+k]] * T[P2[j*3+k]];
            v = acc2;
            int f = l * NA + a2; int aa = f / 35; dest = aa * OC + 50 + (f - aa*35);
        } else if (cc < 160) {
            int l = cc - 85;
            int p2 = l / 5, t = l - p2*5;
            int r = T2I[p2], s = T2J[p2];
            float T[6];
#pragma unroll
            for (int q = 0; q < 6; q++) T[q] = ML(20 + t*6 + q);
            float acc2 = 0.f;
#pragma unroll
            for (int i = 0; i < 3; i++)
#pragma unroll
            for (int j = 0; j < 3; j++)
                acc2 += ML(5 + r*3 + i) * ML(5 + s*3 + j) * T[P2[i*3+j]];
            v = acc2;
            int f = l * NA + a2; int aa = f / 75; dest = aa * OC + 85 + (f - aa*75);
        } else if (cc < 235) {
            int l = cc - 160;
            int p2 = l / 5, t = l - p2*5;
            int r = T2I[p2], s = T2J[p2];
            float R[10], S[10], T[6];
#pragma unroll
            for (int q = 0; q < 10; q++) { R[q]=ML(50+r*10+q); S[q]=ML(50+s*10+q); }
#pragma unroll
            for (int q = 0; q < 6;  q++) T[q] = ML(20 + t*6 + q);
            float acc2 = 0.f;
#pragma unroll
            for (int k = 0; k < 3; k++)
#pragma unroll
            for (int l2 = 0; l2 < 3; l2++) {
                float inner = 0.f;
#pragma unroll
                for (int i = 0; i < 3; i++)
#pragma unroll
                for (int j = 0; j < 3; j++)
                    inner += R[P3[(i*3+j)*3+k]] * S[P3[(i*3+j)*3+l2]];
                acc2 += inner * T[P2[k*3+l2]];
            }
            v = acc2;
            int f = l * NA + a2; int aa = f / 75; dest = aa * OC + 160 + (f - aa*75);
        } else {
            int l = cc - 235;
            int r = l / 25; int rem = l - r*25; int s = rem / 5; int t = rem - s*5;
            float R[10], S[6], T1[3];
#pragma unroll
            for (int q = 0; q < 10; q++) R[q] = ML(50 + r*10 + q);
#pragma unroll
            for (int q = 0; q < 6;  q++) S[q] = ML(20 + s*6 + q);
#pragma unroll
            for (int q = 0; q < 3;  q++) T1[q] = ML(5 + t*3 + q);
            float acc2 = 0.f;
#pragma unroll
            for (int i = 0; i < 3; i++)
#pragma unroll
            for (int j = 0; j < 3; j++)
#pragma unroll
            for (int k = 0; k < 3; k++)
                acc2 += R[P3[(i*3+j)*3+k]] * S[P2[i*3+j]] * T1[k];
            v = acc2;
            int f = l * NA + a2; int aa = f / 125; dest = aa * OC + 235 + (f - aa*125);
        }
        out[dest] = v;
    }
#undef ML
}

// ========================= FALLBACK PATH =======================
__global__ __launch_bounds__(256) void scatter_kernel(
    const int* __restrict__ nbr, int* __restrict__ cursor, int* __restrict__ bins)
{
    int e = blockIdx.x * 256 + threadIdx.x;
    if (e >= NE) return;
    int aj = nbr[NE + e];
    int pos = __hip_atomic_fetch_add(&cursor[aj], 1, __ATOMIC_RELAXED, __HIP_MEMORY_SCOPE_AGENT);
    if (pos < CAPI) bins[(size_t)aj * CAPI + pos] = e;
}

__global__ __launch_bounds__(256) void accum_kernel(
    const float* __restrict__ dr_vec, const int* __restrict__ Z,
    const int* __restrict__ nbr, const float* __restrict__ coeffs,
    const int* __restrict__ cursor, const int* __restrict__ bins,
    float* __restrict__ Mu)
{
    __shared__ float red[32 * MUS];
    int t   = blockIdx.x * 256 + threadIdx.x;
    int a   = t >> 3;
    int sub = t & 7;
    int al  = threadIdx.x >> 3;
    int n   = (a < NA) ? min(cursor[a], CAPI) : 0;
    int Zj  = (a < NA) ? Z[a] : 0;

    float acc[MUS];
#pragma unroll
    for (int i = 0; i < MUS; i++) acc[i] = 0.f;

    const int* mybin = bins + (size_t)a * CAPI;
    const float PI_F = 3.14159265358979323846f;
    const float betta = 49.0f / 36.0f;
    float rad_norm = 0.89812905f;

    for (int p = sub; p < n; p += 8) {
        int e = mybin[p];
        float x = dr_vec[3*e+0], y = dr_vec[3*e+1], z = dr_vec[3*e+2];
        int Zi = Z[nbr[e]];

        float dr  = sqrtf(x*x + y*y + z*z);
        float inv = 1.0f / (dr + 1e-5f);
        float d0 = x*inv, d1 = y*inv, d2 = z*inv;

        float cut = (dr < 6.0f) ? 0.5f*(cosf(PI_F * dr * (1.0f/6.0f)) + 1.0f) : 0.0f;
        float scale = cut * 0.3779644730092272272f * rad_norm;

        float basis[NB];
#pragma unroll
        for (int b = 0; b < NB; b++) {
            float tt = dr - (float)b;
            basis[b] = expf(-betta * tt * tt);
        }

        const float* cp = coeffs + ((size_t)(Zi*NS + Zj)) * (NR*NB);
        float rad[NR];
#pragma unroll
        for (int r = 0; r < NR; r++) {
            float s = 0.f;
#pragma unroll
            for (int b = 0; b < NB; b++) s += basis[b] * cp[r*NB + b];
            rad[r] = s * scale;
        }

        float q2[6] = {d0*d0, d1*d0, d2*d0, d1*d1, d2*d1, d2*d2};
        float q3[10] = {d0*q2[0], d1*q2[0], d0*q2[3], d1*q2[3], d2*q2[0],
                        d2*q2[1], d2*q2[3], d0*q2[5], d1*q2[5], d2*q2[5]};

#pragma unroll
        for (int r = 0; r < NR; r++) {
            float rv = rad[r];
            acc[r] += rv;
            acc[5 + r*3 + 0] += rv*d0;
            acc[5 + r*3 + 1] += rv*d1;
            acc[5 + r*3 + 2] += rv*d2;
#pragma unroll
            for (int q = 0; q < 6; q++)  acc[20 + r*6  + q] += rv*q2[q];
#pragma unroll
            for (int q = 0; q < 10; q++) acc[50 + r*10 + q] += rv*q3[q];
        }
    }

#pragma unroll
    for (int i = 0; i < MUS; i++) {
        float v = acc[i];
        v += __shfl_xor(v, 1, 64);
        v += __shfl_xor(v, 2, 64);
        v += __shfl_xor(v, 4, 64);
        if (sub == 0) red[al * MUS + i] = v;
    }
    __syncthreads();

    for (int u = threadIdx.x; u < 32 * MUS; u += 256) {
        int ga = blockIdx.x * 32 + u / MUS;
        if (ga < NA) Mu[(size_t)ga * MUS + (u - (u / MUS) * MUS)] = red[u];
    }
}

__global__ __launch_bounds__(256) void contract_kernel(
    const float* __restrict__ Mu, float* __restrict__ out)
{
    __shared__ float lds[64 * MPAD];
    int base = blockIdx.x * 64;
    int nat  = min(64, NA - base);

    for (int t = threadIdx.x; t < nat * MUS; t += 256) {
        int al = t / MUS, off = t - al * MUS;
        lds[al * MPAD + off] = Mu[(size_t)base * MUS + t];
    }
    __syncthreads();

    int wave = threadIdx.x >> 6, lane = threadIdx.x & 63;
    int a2 = base + lane;
    bool valid = (lane < nat);
    int mb = lane * MPAD;

#define ML(o) lds[mb + (o)]

    for (int cc = wave; cc < 360; cc += 4) {
        if (!valid) continue;
        float v; int dest;

        if (cc < 5) {
            v = ML(cc);
            dest = a2 * OC + cc;
        } else if (cc < 20) {
            int l = cc - 5;
            int r = T2I[l], s = T2J[l];
            float acc = 0.f;
#pragma unroll
            for (int i = 0; i < 3; i++) acc += ML(5 + r*3 + i) * ML(5 + s*3 + i);
            v = acc;
            int f = l * NA + a2; int aa = f / 15; dest = aa * OC + 5 + (f - aa*15);
        } else if (cc < 35) {
            int l = cc - 20;
            int r = T2I[l], s = T2J[l];
            float acc = 0.f;
#pragma unroll
            for (int p = 0; p < 6; p++) acc += W2[p] * ML(20 + r*6 + p) * ML(20 + s*6 + p);
            v = acc;
            int f = l * NA + a2; int aa = f / 15; dest = aa * OC + 20 + (f - aa*15);
        } else if (cc < 50) {
            int l = cc - 35;
            int r = T2I[l], s = T2J[l];
            float acc = 0.f;
#pragma unroll
            for (int p = 0; p < 10; p++) acc += W3[p] * ML(50 + r*10 + p) * ML(50 + s*10 + p);
            v = acc;
            int f = l * NA + a2; int aa = f / 15; dest = aa * OC + 35 + (f - aa*15);
        } else if (cc < 85) {
            int l = cc - 50;
            int r = T3I[l], s = T3J[l], t = T3K[l];
            float R[6], S[6], T[6];
#pragma unroll
            for (int p = 0; p < 6; p++) { R[p]=ML(20+r*6+p); S[p]=ML(20+s*6+p); T[p]=ML(20+t*6+p); }
            float acc = 0.f;
#pragma unroll
            for (int i = 0; i < 3; i++)
#pragma unroll
            for (int j = 0; j < 3; j++)
#pragma unroll
            for (int k = 0; k < 3; k++)
                acc += R[P2[i*3+j]] * S[P2[i*3+k]] * T[P2[j*3+k]];
            v = acc;
            int f = l * NA + a2; int aa = f / 35; dest = aa * OC + 50 + (f - aa*35);
        } else if (cc < 160) {
            int l = cc - 85;
            int p = l / 5, t = l - p*5;
            int r = T2I[p], s = T2J[p];
            float T[6];
#pragma unroll
            for (int q = 0; q < 6; q++) T[q] = ML(20 + t*6 + q);
            float acc = 0.f;
#pragma unroll
            for (int i = 0; i < 3; i++)
#pragma unroll
            for (int j = 0; j < 3; j++)
                acc += ML(5 + r*3 + i) * ML(5 + s*3 + j) * T[P2[i*3+j]];
            v = acc;
            int f = l * NA + a2; int aa = f / 75; dest = aa * OC + 85 + (f - aa*75);
        } else if (cc < 235) {
            int l = cc - 160;
            int p = l / 5, t = l - p*5;
            int r = T2I[p], s = T2J[p];
            float R[10], S[10], T[6];
#pragma unroll
            for (int q = 0; q < 10; q++) { R[q]=ML(50+r*10+q); S[q]=ML(50+s*10+q); }
#pragma unroll
            for (int q = 0; q < 6;  q++) T[q] = ML(20 + t*6 + q);
            float acc = 0.f;
#pragma unroll
            for (int k = 0; k < 3; k++)
#pragma unroll
            for (int l2 = 0; l2 < 3; l2++) {
                float inner = 0.f;
#pragma unroll
                for (int i = 0; i < 3; i++)
#pragma unroll
                for (int j = 0; j < 3; j++)
                    inner += R[P3[(i*3+j)*3+k]] * S[P3[(i*3+j)*3+l2]];
                acc += inner * T[P2[k*3+l2]];
            }
            v = acc;
            int f = l * NA + a2; int aa = f / 75; dest = aa * OC + 160 + (f - aa*75);
        } else {
            int l = cc - 235;
            int r = l / 25; int rem = l - r*25; int s = rem / 5; int t = rem - s*5;
            float R[10], S[6], T1[3];
#pragma unroll
            for (int q = 0; q < 10; q++) R[q] = ML(50 + r*10 + q);
#pragma unroll
            for (int q = 0; q < 6;  q++) S[q] = ML(20 + s*6 + q);
#pragma unroll
            for (int q = 0; q < 3;  q++) T1[q] = ML(5 + t*3 + q);
            float acc = 0.f;
#pragma unroll
            for (int i = 0; i < 3; i++)
#pragma unroll
            for (int j = 0; j < 3; j++)
#pragma unroll
            for (int k = 0; k < 3; k++)
                acc += R[P3[(i*3+j)*3+k]] * S[P2[i*3+j]] * T1[k];
            v = acc;
            int f = l * NA + a2; int aa = f / 125; dest = aa * OC + 235 + (f - aa*125);
        }
        out[dest] = v;
    }
#undef ML
}

extern "C" void kernel_launch(void* const* d_in, const int* in_sizes, int n_in,
                              void* d_out, int out_size, void* d_ws, size_t ws_size,
                              hipStream_t stream) {
    const float* dr_vec = (const float*)d_in[0];
    const int*   Z      = (const int*)d_in[1];
    const int*   nbr    = (const int*)d_in[2];
    const float* coeffs = (const float*)d_in[3];
    float* out = (float*)d_out;

    // fast path: binrec FIRST (76.8MB, 64B-aligned records), then cursor[NA]
    size_t binrec_fl = (size_t)NA * CAPR * 8;          // floats
    size_t need_fast = binrec_fl * sizeof(float) + (size_t)NA * sizeof(int);

    if (ws_size >= need_fast) {
        float* binrec = (float*)d_ws;
        int*   cursor = (int*)(binrec + binrec_fl);
        hipMemsetAsync(cursor, 0, (size_t)NA * sizeof(int), stream);
        edge_record_kernel<<<(NE + 255)/256, 256, 0, stream>>>(dr_vec, Z, nbr, coeffs, cursor, binrec);
        accum_contract_kernel<<<(NA + CHUNK - 1)/CHUNK, 1024, 0, stream>>>(cursor, binrec, out);
    } else {
        // fallback: cursor[NA] | bins[NA*CAPI] | Mu[NA*MUS] (~21.3 MB)
        int*   cursor = (int*)d_ws;
        int*   bins   = cursor + NA;
        float* Mu     = (float*)(bins + (size_t)NA * CAPI);
        hipMemsetAsync(cursor, 0, (size_t)NA * sizeof(int), stream);
        scatter_kernel<<<(NE + 255)/256, 256, 0, stream>>>(nbr, cursor, bins);
        accum_kernel<<<(NA*8 + 255)/256, 256, 0, stream>>>(dr_vec, Z, nbr, coeffs, cursor, bins, Mu);
        contract_kernel<<<(NA + 63)/64, 256, 0, stream>>>(Mu, out);
    }
}

// Round 11
// 175.039 us; speedup vs baseline: 1.6859x; 1.1022x over previous
//
#include <hip/hip_runtime.h>
#include <math.h>

#define NR 5
#define NB 7
#define NS 119
#define NA 25000
#define NE 1000000
#define OC 360           // output columns per atom
#define MUS 100          // unique moment floats per atom
#define CAPR 96          // record bin capacity (lambda=40, max ~68, overflow ~1e-15)
#define CAPI 112         // id bin capacity (fallback path)
#define CHUNK 64         // atoms per accum/contract block
#define MPAD 101         // LDS stride: gcd(101,32)=1 -> conflict-free

// tril index tables (wave-uniform index -> scalar loads)
static constexpr int T2I[15] = {0,1,1,2,2,2,3,3,3,3,4,4,4,4,4};
static constexpr int T2J[15] = {0,0,1,0,1,2,0,1,2,3,0,1,2,3,4};
static constexpr int T3I[35] = {0,1,1,1,2,2,2,2,2,2,3,3,3,3,3,3,3,3,3,3,4,4,4,4,4,4,4,4,4,4,4,4,4,4,4};
static constexpr int T3J[35] = {0,0,1,1,0,1,1,2,2,2,0,1,1,2,2,2,3,3,3,3,0,1,1,2,2,2,3,3,3,3,4,4,4,4,4};
static constexpr int T3K[35] = {0,0,0,1,0,0,1,0,1,2,0,0,1,0,1,2,0,1,2,3,0,0,1,0,1,2,0,1,2,3,0,1,2,3,4};

static constexpr int P2[9]  = {0,1,2, 1,3,4, 2,4,5};
static constexpr int P3[27] = {0,1,4, 1,2,5, 4,5,7,
                               1,2,5, 2,3,6, 5,6,8,
                               4,5,7, 5,6,8, 7,8,9};
static constexpr float W2[6]  = {1.f,2.f,2.f,1.f,2.f,1.f};
static constexpr float W3[10] = {1.f,3.f,3.f,1.f,3.f,6.f,3.f,3.f,3.f,1.f};

// moment m -> (rad index, product index). P[0]=1, P[1..3]=d, P[4..9]=q2, P[10..19]=q3
static constexpr int MR[100] = {
    0,1,2,3,4,
    0,0,0,1,1,1,2,2,2,3,3,3,4,4,4,
    0,0,0,0,0,0, 1,1,1,1,1,1, 2,2,2,2,2,2, 3,3,3,3,3,3, 4,4,4,4,4,4,
    0,0,0,0,0,0,0,0,0,0, 1,1,1,1,1,1,1,1,1,1, 2,2,2,2,2,2,2,2,2,2,
    3,3,3,3,3,3,3,3,3,3, 4,4,4,4,4,4,4,4,4,4};
static constexpr int MP[100] = {
    0,0,0,0,0,
    1,2,3,1,2,3,1,2,3,1,2,3,1,2,3,
    4,5,6,7,8,9, 4,5,6,7,8,9, 4,5,6,7,8,9, 4,5,6,7,8,9, 4,5,6,7,8,9,
    10,11,12,13,14,15,16,17,18,19, 10,11,12,13,14,15,16,17,18,19,
    10,11,12,13,14,15,16,17,18,19, 10,11,12,13,14,15,16,17,18,19,
    10,11,12,13,14,15,16,17,18,19};

template<int S>
__device__ __forceinline__ void accum25(float acc[25], const float rad[5], const float P[20])
{
#pragma unroll
    for (int i = 0; i < 25; i++)
        acc[i] += rad[MR[S*25 + i]] * P[MP[S*25 + i]];   // all indices compile-time
}

// ============================ FAST PATH ==================================
// R10: 192.9us. Ledger establishes pass 1 is LINE-TOUCH-bound (R4: -31MB
// bytes = no dt; WRITE pinned at 64B/record): ~1M random 64B lines ~ 13G/s
// floor, independent of layout. Pass 2's reads paid the SAME 1M-line cost
// in binrec[atom][pos] layout (lane=atom -> 3KB lane stride, uncoalesced).
// This round: TRANSPOSE bins to binrec[pos][atom]. Write side: still one
// random line per record (cost invariant). Read side: lane a reads record p
// at (p*NA+a)*32B -> 64 lanes = one dense 2KB span, fully coalesced.

// pass 1: fused edge compute + record scatter (R0 structure; slot transposed).
__global__ __launch_bounds__(256) void edge_record_kernel(
    const float* __restrict__ dr_vec, const int* __restrict__ Z,
    const int* __restrict__ nbr, const float* __restrict__ coeffs,
    int* __restrict__ cursor, float* __restrict__ binrec)
{
    int e = blockIdx.x * 256 + threadIdx.x;
    if (e >= NE) return;
    float x = dr_vec[3*e+0], y = dr_vec[3*e+1], z = dr_vec[3*e+2];
    int ai = nbr[e];
    int aj = nbr[NE + e];
    int Zi = Z[ai], Zj = Z[aj];

    float dr  = sqrtf(x*x + y*y + z*z);
    float inv = 1.0f / (dr + 1e-5f);
    float d0 = x*inv, d1 = y*inv, d2 = z*inv;

    const float PI_F = 3.14159265358979323846f;
    const float betta = 49.0f / 36.0f;
    const float rad_norm = 0.89812905f;          // (2*betta/pi)^0.75, folded
    float cut = (dr < 6.0f) ? 0.5f*(cosf(PI_F * dr * (1.0f/6.0f)) + 1.0f) : 0.0f;
    float scale = cut * 0.3779644730092272272f * rad_norm;   // cut/sqrt(7)*norm

    float basis[NB];
#pragma unroll
    for (int b = 0; b < NB; b++) {
        float t = dr - (float)b;
        basis[b] = expf(-betta * t * t);
    }

    const float* cp = coeffs + ((size_t)(Zi*NS + Zj)) * (NR*NB);
    float rad[NR];
#pragma unroll
    for (int r = 0; r < NR; r++) {
        float s = 0.f;
#pragma unroll
        for (int b = 0; b < NB; b++) s += basis[b] * cp[r*NB + b];
        rad[r] = s * scale;
    }

    int pos = __hip_atomic_fetch_add(&cursor[aj], 1, __ATOMIC_RELAXED, __HIP_MEMORY_SCOPE_AGENT);
    if (pos < CAPR) {
        // transposed: row = record index, col = atom -> accum reads coalesce
        float4* rp = (float4*)(binrec + ((size_t)pos * NA + aj) * 8);
        rp[0] = make_float4(rad[0], rad[1], rad[2], rad[3]);
        rp[1] = make_float4(rad[4], d0, d1, d2);
    }
}

// pass 2: accumulate + contract. 1024 threads = 16 waves:
// wave = (sub, slice): slice owns 25 moments (wave-uniform, constant regs),
// sub strides records by 4. Transposed bins: lane=atom, record p read at
// (p*NA + a)*32B -> 64 lanes cover one dense 2KB span (coalesced).
__global__ __launch_bounds__(1024) void accum_contract_kernel(
    const int* __restrict__ cursor, const float* __restrict__ binrec,
    float* __restrict__ out)
{
    __shared__ float lds[CHUNK * MPAD];
    int bl  = blockIdx.x * CHUNK;
    int nat = min(CHUNK, NA - bl);

    int wave  = threadIdx.x >> 6;     // 0..15
    int lane  = threadIdx.x & 63;     // local atom
    int slice = wave & 3;             // moment slice (25 moments)
    int sub   = wave >> 2;            // record subset (stride 4)

    int a = bl + lane;
    int n = (a < NA) ? min(cursor[a], CAPR) : 0;

    float acc[25];
#pragma unroll
    for (int i = 0; i < 25; i++) acc[i] = 0.f;

    const float* bp = binrec + (size_t)a * 8;   // column base for this atom
    for (int p = sub; p < n; p += 4) {
        const float4* rp = (const float4*)(bp + (size_t)p * NA * 8);
        float4 r0 = rp[0], r1 = rp[1];
        float rad[5] = {r0.x, r0.y, r0.z, r0.w, r1.x};
        float d0 = r1.y, d1 = r1.z, d2 = r1.w;

        float P[20];
        P[0] = 1.f; P[1] = d0; P[2] = d1; P[3] = d2;
        P[4] = d0*d0; P[5] = d1*d0; P[6] = d2*d0;
        P[7] = d1*d1; P[8] = d2*d1; P[9] = d2*d2;
        P[10] = d0*P[4]; P[11] = d1*P[4]; P[12] = d0*P[7]; P[13] = d1*P[7];
        P[14] = d2*P[4]; P[15] = d2*P[5]; P[16] = d2*P[7]; P[17] = d0*P[9];
        P[18] = d1*P[9]; P[19] = d2*P[9];

        switch (slice) {              // wave-uniform: no divergence
            case 0: accum25<0>(acc, rad, P); break;
            case 1: accum25<1>(acc, rad, P); break;
            case 2: accum25<2>(acc, rad, P); break;
            default: accum25<3>(acc, rad, P); break;
        }
    }

    // merge the 4 record-subsets: ordered rounds, slices disjoint per round
    float* dst = &lds[lane * MPAD + slice * 25];
    for (int s = 0; s < 4; s++) {
        if (sub == s) {
            if (s == 0) {
#pragma unroll
                for (int i = 0; i < 25; i++) dst[i] = acc[i];
            } else {
#pragma unroll
                for (int i = 0; i < 25; i++) dst[i] += acc[i];
            }
        }
        __syncthreads();
    }

    // ---- contract phase: lanes = atoms, 16 waves split the 360 columns ----
    int a2 = bl + lane;
    bool valid = (lane < nat);
    int mb = lane * MPAD;

#define ML(o) lds[mb + (o)]

    for (int cc = wave; cc < 360; cc += 16) {
        if (!valid) continue;
        float v; int dest;

        if (cc < 5) {
            v = ML(cc);
            dest = a2 * OC + cc;
        } else if (cc < 20) {
            int l = cc - 5;
            int r = T2I[l], s = T2J[l];
            float acc2 = 0.f;
#pragma unroll
            for (int i = 0; i < 3; i++) acc2 += ML(5 + r*3 + i) * ML(5 + s*3 + i);
            v = acc2;
            int f = l * NA + a2; int aa = f / 15; dest = aa * OC + 5 + (f - aa*15);
        } else if (cc < 35) {
            int l = cc - 20;
            int r = T2I[l], s = T2J[l];
            float acc2 = 0.f;
#pragma unroll
            for (int p2 = 0; p2 < 6; p2++) acc2 += W2[p2] * ML(20 + r*6 + p2) * ML(20 + s*6 + p2);
            v = acc2;
            int f = l * NA + a2; int aa = f / 15; dest = aa * OC + 20 + (f - aa*15);
        } else if (cc < 50) {
            int l = cc - 35;
            int r = T2I[l], s = T2J[l];
            float acc2 = 0.f;
#pragma unroll
            for (int p2 = 0; p2 < 10; p2++) acc2 += W3[p2] * ML(50 + r*10 + p2) * ML(50 + s*10 + p2);
            v = acc2;
            int f = l * NA + a2; int aa = f / 15; dest = aa * OC + 35 + (f - aa*15);
        } else if (cc < 85) {
            int l = cc - 50;
            int r = T3I[l], s = T3J[l], t = T3K[l];
            float R[6], S[6], T[6];
#pragma unroll
            for (int p2 = 0; p2 < 6; p2++) { R[p2]=ML(20+r*6+p2); S[p2]=ML(20+s*6+p2); T[p2]=ML(20+t*6+p2); }
            float acc2 = 0.f;
#pragma unroll
            for (int i = 0; i < 3; i++)
#pragma unroll
            for (int j = 0; j < 3; j++)
#pragma unroll
            for (int k = 0; k < 3; k++)
                acc2 += R[P2[i*3+j]] * S[P2[i*3+k]] * T[P2[j*3+k]];
            v = acc2;
            int f = l * NA + a2; int aa = f / 35; dest = aa * OC + 50 + (f - aa*35);
        } else if (cc < 160) {
            int l = cc - 85;
            int p2 = l / 5, t = l - p2*5;
            int r = T2I[p2], s = T2J[p2];
            float T[6];
#pragma unroll
            for (int q = 0; q < 6; q++) T[q] = ML(20 + t*6 + q);
            float acc2 = 0.f;
#pragma unroll
            for (int i = 0; i < 3; i++)
#pragma unroll
            for (int j = 0; j < 3; j++)
                acc2 += ML(5 + r*3 + i) * ML(5 + s*3 + j) * T[P2[i*3+j]];
            v = acc2;
            int f = l * NA + a2; int aa = f / 75; dest = aa * OC + 85 + (f - aa*75);
        } else if (cc < 235) {
            int l = cc - 160;
            int p2 = l / 5, t = l - p2*5;
            int r = T2I[p2], s = T2J[p2];
            float R[10], S[10], T[6];
#pragma unroll
            for (int q = 0; q < 10; q++) { R[q]=ML(50+r*10+q); S[q]=ML(50+s*10+q); }
#pragma unroll
            for (int q = 0; q < 6;  q++) T[q] = ML(20 + t*6 + q);
            float acc2 = 0.f;
#pragma unroll
            for (int k = 0; k < 3; k++)
#pragma unroll
            for (int l2 = 0; l2 < 3; l2++) {
                float inner = 0.f;
#pragma unroll
                for (int i = 0; i < 3; i++)
#pragma unroll
                for (int j = 0; j < 3; j++)
                    inner += R[P3[(i*3+j)*3+k]] * S[P3[(i*3+j)*3+l2]];
                acc2 += inner * T[P2[k*3+l2]];
            }
            v = acc2;
            int f = l * NA + a2; int aa = f / 75; dest = aa * OC + 160 + (f - aa*75);
        } else {
            int l = cc - 235;
            int r = l / 25; int rem = l - r*25; int s = rem / 5; int t = rem - s*5;
            float R[10], S[6], T1[3];
#pragma unroll
            for (int q = 0; q < 10; q++) R[q] = ML(50 + r*10 + q);
#pragma unroll
            for (int q = 0; q < 6;  q++) S[q] = ML(20 + s*6 + q);
#pragma unroll
            for (int q = 0; q < 3;  q++) T1[q] = ML(5 + t*3 + q);
            float acc2 = 0.f;
#pragma unroll
            for (int i = 0; i < 3; i++)
#pragma unroll
            for (int j = 0; j < 3; j++)
#pragma unroll
            for (int k = 0; k < 3; k++)
                acc2 += R[P3[(i*3+j)*3+k]] * S[P2[i*3+j]] * T1[k];
            v = acc2;
            int f = l * NA + a2; int aa = f / 125; dest = aa * OC + 235 + (f - aa*125);
        }
        out[dest] = v;
    }
#undef ML
}

// ========================= FALLBACK PATH =======================
__global__ __launch_bounds__(256) void scatter_kernel(
    const int* __restrict__ nbr, int* __restrict__ cursor, int* __restrict__ bins)
{
    int e = blockIdx.x * 256 + threadIdx.x;
    if (e >= NE) return;
    int aj = nbr[NE + e];
    int pos = __hip_atomic_fetch_add(&cursor[aj], 1, __ATOMIC_RELAXED, __HIP_MEMORY_SCOPE_AGENT);
    if (pos < CAPI) bins[(size_t)aj * CAPI + pos] = e;
}

__global__ __launch_bounds__(256) void accum_kernel(
    const float* __restrict__ dr_vec, const int* __restrict__ Z,
    const int* __restrict__ nbr, const float* __restrict__ coeffs,
    const int* __restrict__ cursor, const int* __restrict__ bins,
    float* __restrict__ Mu)
{
    __shared__ float red[32 * MUS];
    int t   = blockIdx.x * 256 + threadIdx.x;
    int a   = t >> 3;
    int sub = t & 7;
    int al  = threadIdx.x >> 3;
    int n   = (a < NA) ? min(cursor[a], CAPI) : 0;
    int Zj  = (a < NA) ? Z[a] : 0;

    float acc[MUS];
#pragma unroll
    for (int i = 0; i < MUS; i++) acc[i] = 0.f;

    const int* mybin = bins + (size_t)a * CAPI;
    const float PI_F = 3.14159265358979323846f;
    const float betta = 49.0f / 36.0f;
    float rad_norm = 0.89812905f;

    for (int p = sub; p < n; p += 8) {
        int e = mybin[p];
        float x = dr_vec[3*e+0], y = dr_vec[3*e+1], z = dr_vec[3*e+2];
        int Zi = Z[nbr[e]];

        float dr  = sqrtf(x*x + y*y + z*z);
        float inv = 1.0f / (dr + 1e-5f);
        float d0 = x*inv, d1 = y*inv, d2 = z*inv;

        float cut = (dr < 6.0f) ? 0.5f*(cosf(PI_F * dr * (1.0f/6.0f)) + 1.0f) : 0.0f;
        float scale = cut * 0.3779644730092272272f * rad_norm;

        float basis[NB];
#pragma unroll
        for (int b = 0; b < NB; b++) {
            float tt = dr - (float)b;
            basis[b] = expf(-betta * tt * tt);
        }

        const float* cp = coeffs + ((size_t)(Zi*NS + Zj)) * (NR*NB);
        float rad[NR];
#pragma unroll
        for (int r = 0; r < NR; r++) {
            float s = 0.f;
#pragma unroll
            for (int b = 0; b < NB; b++) s += basis[b] * cp[r*NB + b];
            rad[r] = s * scale;
        }

        float q2[6] = {d0*d0, d1*d0, d2*d0, d1*d1, d2*d1, d2*d2};
        float q3[10] = {d0*q2[0], d1*q2[0], d0*q2[3], d1*q2[3], d2*q2[0],
                        d2*q2[1], d2*q2[3], d0*q2[5], d1*q2[5], d2*q2[5]};

#pragma unroll
        for (int r = 0; r < NR; r++) {
            float rv = rad[r];
            acc[r] += rv;
            acc[5 + r*3 + 0] += rv*d0;
            acc[5 + r*3 + 1] += rv*d1;
            acc[5 + r*3 + 2] += rv*d2;
#pragma unroll
            for (int q = 0; q < 6; q++)  acc[20 + r*6  + q] += rv*q2[q];
#pragma unroll
            for (int q = 0; q < 10; q++) acc[50 + r*10 + q] += rv*q3[q];
        }
    }

#pragma unroll
    for (int i = 0; i < MUS; i++) {
        float v = acc[i];
        v += __shfl_xor(v, 1, 64);
        v += __shfl_xor(v, 2, 64);
        v += __shfl_xor(v, 4, 64);
        if (sub == 0) red[al * MUS + i] = v;
    }
    __syncthreads();

    for (int u = threadIdx.x; u < 32 * MUS; u += 256) {
        int ga = blockIdx.x * 32 + u / MUS;
        if (ga < NA) Mu[(size_t)ga * MUS + (u - (u / MUS) * MUS)] = red[u];
    }
}

__global__ __launch_bounds__(256) void contract_kernel(
    const float* __restrict__ Mu, float* __restrict__ out)
{
    __shared__ float lds[64 * MPAD];
    int base = blockIdx.x * 64;
    int nat  = min(64, NA - base);

    for (int t = threadIdx.x; t < nat * MUS; t += 256) {
        int al = t / MUS, off = t - al * MUS;
        lds[al * MPAD + off] = Mu[(size_t)base * MUS + t];
    }
    __syncthreads();

    int wave = threadIdx.x >> 6, lane = threadIdx.x & 63;
    int a2 = base + lane;
    bool valid = (lane < nat);
    int mb = lane * MPAD;

#define ML(o) lds[mb + (o)]

    for (int cc = wave; cc < 360; cc += 4) {
        if (!valid) continue;
        float v; int dest;

        if (cc < 5) {
            v = ML(cc);
            dest = a2 * OC + cc;
        } else if (cc < 20) {
            int l = cc - 5;
            int r = T2I[l], s = T2J[l];
            float acc = 0.f;
#pragma unroll
            for (int i = 0; i < 3; i++) acc += ML(5 + r*3 + i) * ML(5 + s*3 + i);
            v = acc;
            int f = l * NA + a2; int aa = f / 15; dest = aa * OC + 5 + (f - aa*15);
        } else if (cc < 35) {
            int l = cc - 20;
            int r = T2I[l], s = T2J[l];
            float acc = 0.f;
#pragma unroll
            for (int p = 0; p < 6; p++) acc += W2[p] * ML(20 + r*6 + p) * ML(20 + s*6 + p);
            v = acc;
            int f = l * NA + a2; int aa = f / 15; dest = aa * OC + 20 + (f - aa*15);
        } else if (cc < 50) {
            int l = cc - 35;
            int r = T2I[l], s = T2J[l];
            float acc = 0.f;
#pragma unroll
            for (int p = 0; p < 10; p++) acc += W3[p] * ML(50 + r*10 + p) * ML(50 + s*10 + p);
            v = acc;
            int f = l * NA + a2; int aa = f / 15; dest = aa * OC + 35 + (f - aa*15);
        } else if (cc < 85) {
            int l = cc - 50;
            int r = T3I[l], s = T3J[l], t = T3K[l];
            float R[6], S[6], T[6];
#pragma unroll
            for (int p = 0; p < 6; p++) { R[p]=ML(20+r*6+p); S[p]=ML(20+s*6+p); T[p]=ML(20+t*6+p); }
            float acc = 0.f;
#pragma unroll
            for (int i = 0; i < 3; i++)
#pragma unroll
            for (int j = 0; j < 3; j++)
#pragma unroll
            for (int k = 0; k < 3; k++)
                acc += R[P2[i*3+j]] * S[P2[i*3+k]] * T[P2[j*3+k]];
            v = acc;
            int f = l * NA + a2; int aa = f / 35; dest = aa * OC + 50 + (f - aa*35);
        } else if (cc < 160) {
            int l = cc - 85;
            int p = l / 5, t = l - p*5;
            int r = T2I[p], s = T2J[p];
            float T[6];
#pragma unroll
            for (int q = 0; q < 6; q++) T[q] = ML(20 + t*6 + q);
            float acc = 0.f;
#pragma unroll
            for (int i = 0; i < 3; i++)
#pragma unroll
            for (int j = 0; j < 3; j++)
                acc += ML(5 + r*3 + i) * ML(5 + s*3 + j) * T[P2[i*3+j]];
            v = acc;
            int f = l * NA + a2; int aa = f / 75; dest = aa * OC + 85 + (f - aa*75);
        } else if (cc < 235) {
            int l = cc - 160;
            int p = l / 5, t = l - p*5;
            int r = T2I[p], s = T2J[p];
            float R[10], S[10], T[6];
#pragma unroll
            for (int q = 0; q < 10; q++) { R[q]=ML(50+r*10+q); S[q]=ML(50+s*10+q); }
#pragma unroll
            for (int q = 0; q < 6;  q++) T[q] = ML(20 + t*6 + q);
            float acc = 0.f;
#pragma unroll
            for (int k = 0; k < 3; k++)
#pragma unroll
            for (int l2 = 0; l2 < 3; l2++) {
                float inner = 0.f;
#pragma unroll
                for (int i = 0; i < 3; i++)
#pragma unroll
                for (int j = 0; j < 3; j++)
                    inner += R[P3[(i*3+j)*3+k]] * S[P3[(i*3+j)*3+l2]];
                acc += inner * T[P2[k*3+l2]];
            }
            v = acc;
            int f = l * NA + a2; int aa = f / 75; dest = aa * OC + 160 + (f - aa*75);
        } else {
            int l = cc - 235;
            int r = l / 25; int rem = l - r*25; int s = rem / 5; int t = rem - s*5;
            float R[10], S[6], T1[3];
#pragma unroll
            for (int q = 0; q < 10; q++) R[q] = ML(50 + r*10 + q);
#pragma unroll
            for (int q = 0; q < 6;  q++) S[q] = ML(20 + s*6 + q);
#pragma unroll
            for (int q = 0; q < 3;  q++) T1[q] = ML(5 + t*3 + q);
            float acc = 0.f;
#pragma unroll
            for (int i = 0; i < 3; i++)
#pragma unroll
            for (int j = 0; j < 3; j++)
#pragma unroll
            for (int k = 0; k < 3; k++)
                acc += R[P3[(i*3+j)*3+k]] * S[P2[i*3+j]] * T1[k];
            v = acc;
            int f = l * NA + a2; int aa = f / 125; dest = aa * OC + 235 + (f - aa*125);
        }
        out[dest] = v;
    }
#undef ML
}

extern "C" void kernel_launch(void* const* d_in, const int* in_sizes, int n_in,
                              void* d_out, int out_size, void* d_ws, size_t ws_size,
                              hipStream_t stream) {
    const float* dr_vec = (const float*)d_in[0];
    const int*   Z      = (const int*)d_in[1];
    const int*   nbr    = (const int*)d_in[2];
    const float* coeffs = (const float*)d_in[3];
    float* out = (float*)d_out;

    // fast path: binrec FIRST (76.8MB, 64B-aligned), then cursor[NA]
    size_t binrec_fl = (size_t)NA * CAPR * 8;          // floats
    size_t need_fast = binrec_fl * sizeof(float) + (size_t)NA * sizeof(int);

    if (ws_size >= need_fast) {
        float* binrec = (float*)d_ws;
        int*   cursor = (int*)(binrec + binrec_fl);
        hipMemsetAsync(cursor, 0, (size_t)NA * sizeof(int), stream);
        edge_record_kernel<<<(NE + 255)/256, 256, 0, stream>>>(dr_vec, Z, nbr, coeffs, cursor, binrec);
        accum_contract_kernel<<<(NA + CHUNK - 1)/CHUNK, 1024, 0, stream>>>(cursor, binrec, out);
    } else {
        // fallback: cursor[NA] | bins[NA*CAPI] | Mu[NA*MUS] (~21.3 MB)
        int*   cursor = (int*)d_ws;
        int*   bins   = cursor + NA;
        float* Mu     = (float*)(bins + (size_t)NA * CAPI);
        hipMemsetAsync(cursor, 0, (size_t)NA * sizeof(int), stream);
        scatter_kernel<<<(NE + 255)/256, 256, 0, stream>>>(nbr, cursor, bins);
        accum_kernel<<<(NA*8 + 255)/256, 256, 0, stream>>>(dr_vec, Z, nbr, coeffs, cursor, bins, Mu);
        contract_kernel<<<(NA + 63)/64, 256, 0, stream>>>(Mu, out);
    }
}